// Round 3
// baseline (427.955 us; speedup 1.0000x reference)
//
#include <hip/hip_runtime.h>
#include <math.h>

// N = 100000 nodes, SEQ = 16, layers: 3 ->16 ->32 ->64 ->128 ->256 ->12(log_softmax)
// bf16 MFMA path, barrier-light K-loop:
//   A (gathered) goes global->VGPR directly (16B frags), prefetched one step ahead.
//   B double-buffered in LDS (XOR-swizzled, conflict-free), ONE barrier per step.

typedef __bf16 bf16x8 __attribute__((ext_vector_type(8)));
typedef float f32x16 __attribute__((ext_vector_type(16)));

__device__ __forceinline__ float elu_f(float v) { return v > 0.f ? v : expm1f(v); }

// ------------------------------------------------ fused fp32 -> bf16 weight conversion
__global__ __launch_bounds__(256) void cvt5_kernel(const float* __restrict__ a, int na,
                                                   const float* __restrict__ b, int nb,
                                                   const float* __restrict__ c, int nc,
                                                   const float* __restrict__ d, int nd,
                                                   const float* __restrict__ e, int ne,
                                                   __bf16* __restrict__ dst)
{
    int i = blockIdx.x * 256 + threadIdx.x;
    int t01 = na + nb, t02 = t01 + nc, t03 = t02 + nd, t04 = t03 + ne;
    if (i >= t04) return;
    float v;
    if (i < na)       v = a[i];
    else if (i < t01) v = b[i - na];
    else if (i < t02) v = c[i - t01];
    else if (i < t03) v = d[i - t02];
    else              v = e[i - t03];
    dst[i] = (__bf16)v;
}

// ---------------------------------------------------------------- fc0: [N,3] -> [N,16] bf16
__global__ __launch_bounds__(256) void fc0_kernel(const float* __restrict__ x,
                                                  const float* __restrict__ w,
                                                  const float* __restrict__ b,
                                                  __bf16* __restrict__ h0, int N)
{
    int n = blockIdx.x * 256 + threadIdx.x;
    if (n >= N) return;
    float x0 = x[n * 3 + 0], x1 = x[n * 3 + 1], x2 = x[n * 3 + 2];
    __bf16 ob[16];
#pragma unroll
    for (int j = 0; j < 16; ++j)
        ob[j] = (__bf16)elu_f(w[j * 3 + 0] * x0 + w[j * 3 + 1] * x1 + w[j * 3 + 2] * x2 + b[j]);
    int4* dst = (int4*)&h0[(size_t)n * 16];
    dst[0] = *(int4*)&ob[0];
    dst[1] = *(int4*)&ob[8];
}

// ------------------------------------------- MFMA gather-GEMM, barrier-light
// out[n,o] = elu( sum_k A[n,k] * W[o,k] + bias[o] ),  A[n, s*CIN+c] = hin[idx[n,s], c]
template <int CIN, int S, int COUT, int TILE_M, int RW, int CW, bool GATHER>
__global__ __launch_bounds__(256) void mfma_layer(const __bf16* __restrict__ hin,
                                                  const int* __restrict__ idx,
                                                  const __bf16* __restrict__ Wb,
                                                  const float* __restrict__ bias,
                                                  __bf16* __restrict__ hout, int N)
{
    constexpr int K = CIN * S;
    constexpr int NSTEP = K / 64;
    static_assert(K % 64 == 0, "K%64");
    constexpr int WM = TILE_M / RW;   // rows per wave
    constexpr int WN = COUT / CW;     // cols per wave
    constexpr int MT = WM / 32;
    constexpr int NT = WN / 32;
    constexpr int IPS = GATHER ? (64 / CIN > 0 ? 64 / CIN : 1) : 1;  // neighbors per step
    constexpr int CPT = (COUT * 8) / 256;  // B 16B-chunks per thread per step
    static_assert(RW * CW == 4, "4 waves");
    static_assert(WM % 32 == 0 && WN % 32 == 0, "tile mult of 32");
    static_assert(CPT >= 1, "B chunk split");

    // B tiles, double buffered; 16B chunk c of row n stored at chunk (c ^ (n&7)).
    __shared__ __align__(16) __bf16 Bs[2][COUT][64];

    const int tid = threadIdx.x;
    const int lane = tid & 63;
    const int w = tid >> 6;
    const int wr = w / CW;
    const int wc = w % CW;
    const int ml = lane & 31;
    const int kh = lane >> 5;
    const int m0 = blockIdx.x * TILE_M;

    int4 breg[CPT];
    auto loadB = [&](int step) {
#pragma unroll
        for (int c = 0; c < CPT; ++c) {
            int chunk = tid + c * 256;
            int n = chunk >> 3, k8 = chunk & 7;
            breg[c] = *(const int4*)&Wb[(size_t)n * K + step * 64 + k8 * 8];
        }
    };
    auto storeB = [&](int buf) {
#pragma unroll
        for (int c = 0; c < CPT; ++c) {
            int chunk = tid + c * 256;
            int n = chunk >> 3, k8 = chunk & 7;
            *(int4*)&Bs[buf][n][(k8 ^ (n & 7)) * 8] = breg[c];
        }
    };

    bf16x8 afr[MT][4];
    int nidx[MT][IPS];
    auto loadIdx = [&](int step) {
        if constexpr (GATHER) {
#pragma unroll
            for (int mi = 0; mi < MT; ++mi) {
                int gm = m0 + wr * WM + mi * 32 + ml;
                if (gm >= N) gm = N - 1;
                if constexpr (IPS == 4) {
                    int4 t = *(const int4*)&idx[(size_t)gm * S + step * 4];
                    nidx[mi][0] = t.x; nidx[mi][1] = t.y; nidx[mi][2] = t.z; nidx[mi][3] = t.w;
                } else if constexpr (IPS == 2) {
                    int2 t = *(const int2*)&idx[(size_t)gm * S + step * 2];
                    nidx[mi][0] = t.x; nidx[mi][1] = t.y;
                } else {
                    nidx[mi][0] = idx[(size_t)gm * S + step];
                }
            }
        }
    };
    auto loadA = [&](int step, int mi, int ks) {
        if constexpr (GATHER) {
            int node = nidx[mi][(ks * IPS) / 4];
            int koff = (ks * 16 + kh * 8) % CIN;
            afr[mi][ks] = *(const bf16x8*)&hin[(size_t)node * CIN + koff];
        } else {
            int gm = m0 + wr * WM + mi * 32 + ml;
            if (gm >= N) gm = N - 1;
            afr[mi][ks] = *(const bf16x8*)&hin[(size_t)gm * K + step * 64 + ks * 16 + kh * 8];
        }
    };

    f32x16 acc[MT][NT];
#pragma unroll
    for (int mi = 0; mi < MT; ++mi)
#pragma unroll
        for (int ni = 0; ni < NT; ++ni) {
            f32x16 z = {};
            acc[mi][ni] = z;
        }

    // ---- init: stage B[0] (and B[1] if only 2 steps), prefetch A[0]
    loadB(0);
    storeB(0);
    loadIdx(0);
#pragma unroll
    for (int mi = 0; mi < MT; ++mi)
#pragma unroll
        for (int ks = 0; ks < 4; ++ks) loadA(0, mi, ks);
    if constexpr (NSTEP == 2) { loadB(1); storeB(1); }
    __syncthreads();

#pragma unroll
    for (int step = 0; step < NSTEP; ++step) {
        const bool more = (step + 1 < NSTEP);
        if (more && NSTEP > 2) loadB(step + 1);   // global loads in flight during MFMAs
        if (more) loadIdx(step + 1);
#pragma unroll
        for (int ks = 0; ks < 4; ++ks) {
            const int cb = ks * 2 + kh;           // logical 16B chunk within the 64-wide step
            bf16x8 bfr[NT];
#pragma unroll
            for (int ni = 0; ni < NT; ++ni) {
                int col = wc * WN + ni * 32 + ml;
                bfr[ni] = *(const bf16x8*)&Bs[step & 1][col][(cb ^ (col & 7)) * 8];
            }
#pragma unroll
            for (int mi = 0; mi < MT; ++mi)
#pragma unroll
                for (int ni = 0; ni < NT; ++ni)
                    acc[mi][ni] = __builtin_amdgcn_mfma_f32_32x32x16_bf16(afr[mi][ks], bfr[ni], acc[mi][ni], 0, 0, 0);
            if (more) {
#pragma unroll
                for (int mi = 0; mi < MT; ++mi) loadA(step + 1, mi, ks);  // prefetch next step's A
            }
        }
        if (more && NSTEP > 2) {
            storeB((step + 1) & 1);
            __syncthreads();
        }
    }

    // ---- epilogue: bias + ELU + bf16 store
#pragma unroll
    for (int ni = 0; ni < NT; ++ni) {
        const int colg = wc * WN + ni * 32 + ml;
        const float bv = bias[colg];
#pragma unroll
        for (int mi = 0; mi < MT; ++mi) {
#pragma unroll
            for (int r = 0; r < 16; ++r) {
                int mrow = wr * WM + mi * 32 + ((r & 3) + 8 * (r >> 2) + 4 * kh);
                int gm = m0 + mrow;
                if (gm < N)
                    hout[(size_t)gm * COUT + colg] = (__bf16)elu_f(acc[mi][ni][r] + bv);
            }
        }
    }
}

// ---------------------------------------------------------------- fc2 + log_softmax: [N,256] bf16 -> [N,12] f32
__global__ __launch_bounds__(256) void fc2_kernel(const __bf16* __restrict__ h4,
                                                  const __bf16* __restrict__ Wb,  // [12,256] bf16
                                                  const float* __restrict__ bias,
                                                  float* __restrict__ out, int N)
{
    const int lane = threadIdx.x & 63;
    const int w = threadIdx.x >> 6;
    const int c = lane & 31;   // k-chunk (8 bf16 each)
    const int half = lane >> 5;

    bf16x8 wreg[12];
#pragma unroll
    for (int o = 0; o < 12; ++o)
        wreg[o] = *(const bf16x8*)&Wb[o * 256 + c * 8];

    const int base = blockIdx.x * 32 + w * 8;
#pragma unroll
    for (int p = 0; p < 4; ++p) {
        int n = base + p * 2 + half;
        bool valid = n < N;
        int nn = valid ? n : N - 1;
        bf16x8 h = *(const bf16x8*)&h4[(size_t)nn * 256 + c * 8];
        float hf[8];
#pragma unroll
        for (int j = 0; j < 8; ++j) hf[j] = (float)h[j];
        float pr[12];
#pragma unroll
        for (int o = 0; o < 12; ++o) {
            float s = 0.f;
#pragma unroll
            for (int j = 0; j < 8; ++j) s += hf[j] * (float)wreg[o][j];
            pr[o] = s;
        }
#pragma unroll
        for (int off = 16; off > 0; off >>= 1) {
#pragma unroll
            for (int o = 0; o < 12; ++o) pr[o] += __shfl_down(pr[o], off, 32);
        }
        if (c == 0 && valid) {
            float logits[12], mx = -1e30f;
#pragma unroll
            for (int o = 0; o < 12; ++o) {
                logits[o] = pr[o] + bias[o];
                mx = fmaxf(mx, logits[o]);
            }
            float s = 0.f;
#pragma unroll
            for (int o = 0; o < 12; ++o) s += expf(logits[o] - mx);
            float lse = mx + logf(s);
#pragma unroll
            for (int o = 0; o < 12; ++o) out[(size_t)n * 12 + o] = logits[o] - lse;
        }
    }
}

extern "C" void kernel_launch(void* const* d_in, const int* in_sizes, int n_in,
                              void* d_out, int out_size, void* d_ws, size_t ws_size,
                              hipStream_t stream)
{
    const int N = 100000;
    const float* x     = (const float*)d_in[0];
    const int*   idx   = (const int*)  d_in[1];
    const float* fc0_w = (const float*)d_in[2];
    const float* fc0_b = (const float*)d_in[3];
    const float* w1    = (const float*)d_in[4];
    const float* b1    = (const float*)d_in[5];
    const float* w2    = (const float*)d_in[6];
    const float* b2    = (const float*)d_in[7];
    const float* w3    = (const float*)d_in[8];
    const float* b3    = (const float*)d_in[9];
    const float* fc1_w = (const float*)d_in[10];
    const float* fc1_b = (const float*)d_in[11];
    const float* fc2_w = (const float*)d_in[12];
    const float* fc2_b = (const float*)d_in[13];
    float* out = (float*)d_out;

    // ---- workspace layout (bf16 everywhere), ~100 MB total
    char* ws = (char*)d_ws;
    const int n_w1 = 32 * 256, n_w2 = 64 * 512, n_w3 = 128 * 1024, n_fc1 = 256 * 128, n_fc2 = 12 * 256;
    const int n_wb = n_w1 + n_w2 + n_w3 + n_fc1 + n_fc2;
    __bf16* wb  = (__bf16*)ws;
    __bf16* w1b = wb;
    __bf16* w2b = w1b + n_w1;
    __bf16* w3b = w2b + n_w2;
    __bf16* f1b = w3b + n_w3;
    __bf16* f2b = f1b + n_fc1;
    size_t off = ((size_t)n_wb * 2 + 4095) & ~(size_t)4095;
    __bf16* h0 = (__bf16*)(ws + off);  off += (size_t)N * 16 * 2;
    __bf16* h1 = (__bf16*)(ws + off);  off += (size_t)N * 32 * 2;
    __bf16* h2 = (__bf16*)(ws + off);  off += (size_t)N * 64 * 2;
    __bf16* h3 = (__bf16*)(ws + off);  off += (size_t)N * 128 * 2;
    __bf16* h4 = (__bf16*)(ws + off);  off += (size_t)N * 256 * 2;

    cvt5_kernel<<<(n_wb + 255) / 256, 256, 0, stream>>>(w1, n_w1, w2, n_w2, w3, n_w3,
                                                        fc1_w, n_fc1, fc2_w, n_fc2, wb);
    fc0_kernel<<<(N + 255) / 256, 256, 0, stream>>>(x, fc0_w, fc0_b, h0, N);
    // spiral1: 16ch x16 -> 32   (wave tile 32x32)
    mfma_layer<16, 16, 32, 128, 4, 1, true><<<(N + 127) / 128, 256, 0, stream>>>(h0, idx, w1b, b1, h1, N);
    // spiral2: 32ch x16 -> 64   (wave tile 64x32)
    mfma_layer<32, 16, 64, 128, 2, 2, true><<<(N + 127) / 128, 256, 0, stream>>>(h1, idx, w2b, b2, h2, N);
    // spiral3: 64ch x16 -> 128  (wave tile 64x64)
    mfma_layer<64, 16, 128, 128, 2, 2, true><<<(N + 127) / 128, 256, 0, stream>>>(h2, idx, w3b, b3, h3, N);
    // fc1: dense 128 -> 256     (wave tile 64x64, 2 steps, no in-loop barriers)
    mfma_layer<128, 1, 256, 64, 1, 4, false><<<(N + 63) / 64, 256, 0, stream>>>(h3, nullptr, f1b, fc1_b, h4, N);
    // fc2 + log_softmax
    fc2_kernel<<<(N + 31) / 32, 256, 0, stream>>>(h4, f2b, fc2_b, out, N);
}

// Round 4
// 424.141 us; speedup vs baseline: 1.0090x; 1.0090x over previous
//
#include <hip/hip_runtime.h>
#include <math.h>

// N = 100000 nodes, SEQ = 16, layers: 3 ->16 ->32 ->64 ->128 ->256 ->12(log_softmax)
// bf16 MFMA path, barrier-light K-loop:
//   A (gathered) global->VGPR directly (16B frags), prefetched one full step ahead.
//   idx prefetched two steps ahead (double-buffered in regs).
//   B staged to LDS via global_load_lds DMA (zero VGPR cost), k-major layout
//   (chunk L = k8*COUT + n) -> linear DMA dst AND conflict-free ds_read_b128.
//   ONE barrier per K-step (none in-loop for NSTEP==2).

typedef __bf16 bf16x8 __attribute__((ext_vector_type(8)));
typedef float f32x16 __attribute__((ext_vector_type(16)));

__device__ __forceinline__ float elu_f(float v) { return v > 0.f ? v : expm1f(v); }

// ------------------------------------------------ fused fp32 -> bf16 weight conversion
__global__ __launch_bounds__(256) void cvt5_kernel(const float* __restrict__ a, int na,
                                                   const float* __restrict__ b, int nb,
                                                   const float* __restrict__ c, int nc,
                                                   const float* __restrict__ d, int nd,
                                                   const float* __restrict__ e, int ne,
                                                   __bf16* __restrict__ dst)
{
    int i = blockIdx.x * 256 + threadIdx.x;
    int t01 = na + nb, t02 = t01 + nc, t03 = t02 + nd, t04 = t03 + ne;
    if (i >= t04) return;
    float v;
    if (i < na)       v = a[i];
    else if (i < t01) v = b[i - na];
    else if (i < t02) v = c[i - t01];
    else if (i < t03) v = d[i - t02];
    else              v = e[i - t03];
    dst[i] = (__bf16)v;
}

// ---------------------------------------------------------------- fc0: [N,3] -> [N,16] bf16
__global__ __launch_bounds__(256) void fc0_kernel(const float* __restrict__ x,
                                                  const float* __restrict__ w,
                                                  const float* __restrict__ b,
                                                  __bf16* __restrict__ h0, int N)
{
    int n = blockIdx.x * 256 + threadIdx.x;
    if (n >= N) return;
    float x0 = x[n * 3 + 0], x1 = x[n * 3 + 1], x2 = x[n * 3 + 2];
    __bf16 ob[16];
#pragma unroll
    for (int j = 0; j < 16; ++j)
        ob[j] = (__bf16)elu_f(w[j * 3 + 0] * x0 + w[j * 3 + 1] * x1 + w[j * 3 + 2] * x2 + b[j]);
    int4* dst = (int4*)&h0[(size_t)n * 16];
    dst[0] = *(int4*)&ob[0];
    dst[1] = *(int4*)&ob[8];
}

// ------------------------------------------- MFMA gather-GEMM, barrier-light
// out[n,o] = elu( sum_k A[n,k] * W[o,k] + bias[o] ),  A[n, s*CIN+c] = hin[idx[n,s], c]
template <int CIN, int S, int COUT, int TILE_M, int RW, int CW, bool GATHER, int MINW>
__global__ __launch_bounds__(256, MINW) void mfma_layer(const __bf16* __restrict__ hin,
                                                        const int* __restrict__ idx,
                                                        const __bf16* __restrict__ Wb,
                                                        const float* __restrict__ bias,
                                                        __bf16* __restrict__ hout, int N)
{
    constexpr int K = CIN * S;
    constexpr int NSTEP = K / 64;
    static_assert(K % 64 == 0, "K%64");
    constexpr int WM = TILE_M / RW;   // rows per wave
    constexpr int WN = COUT / CW;     // cols per wave
    constexpr int MT = WM / 32;
    constexpr int NT = WN / 32;
    constexpr int IPS = GATHER ? (64 / CIN > 0 ? 64 / CIN : 1) : 1;  // neighbors per step
    constexpr int CPT = (COUT * 8) / 256;  // B 16B-chunks per thread per step
    static_assert(RW * CW == 4, "4 waves");
    static_assert(WM % 32 == 0 && WN % 32 == 0, "tile mult of 32");
    static_assert(CPT >= 1, "B chunk split");

    // B double-buffered, k-major 16B chunks: chunk (k8, n) lives at index k8*COUT + n.
    __shared__ __align__(16) int4 Bs[2][COUT * 8];

    const int tid = threadIdx.x;
    const int lane = tid & 63;
    const int w = tid >> 6;
    const int wr = w / CW;
    const int wc = w % CW;
    const int ml = lane & 31;
    const int kh = lane >> 5;
    const int m0 = blockIdx.x * TILE_M;

    // ---- B staging: DMA straight to LDS, zero VGPR footprint.
    auto stageB = [&](int step, int buf) {
#pragma unroll
        for (int c = 0; c < CPT; ++c) {
            int L = tid + c * 256;          // linear chunk: dst = base + tid*16 (DMA-legal)
            int k8 = L / COUT;              // pow2
            int n  = L % COUT;
            const __bf16* src = Wb + (size_t)n * K + step * 64 + k8 * 8;
            __builtin_amdgcn_global_load_lds(
                (const __attribute__((address_space(1))) void*)src,
                (__attribute__((address_space(3))) void*)&Bs[buf][L],
                16, 0, 0);
        }
    };

    bf16x8 afr[MT][4];
    int nidx[2][MT][IPS];
    auto loadIdx = [&](int step) {
        if constexpr (GATHER) {
            if (step >= NSTEP) return;
            const int sl = step & 1;
#pragma unroll
            for (int mi = 0; mi < MT; ++mi) {
                int gm = m0 + wr * WM + mi * 32 + ml;
                if (gm >= N) gm = N - 1;
                if constexpr (IPS == 4) {
                    int4 t = *(const int4*)&idx[(size_t)gm * S + step * 4];
                    nidx[sl][mi][0] = t.x; nidx[sl][mi][1] = t.y;
                    nidx[sl][mi][2] = t.z; nidx[sl][mi][3] = t.w;
                } else if constexpr (IPS == 2) {
                    int2 t = *(const int2*)&idx[(size_t)gm * S + step * 2];
                    nidx[sl][mi][0] = t.x; nidx[sl][mi][1] = t.y;
                } else {
                    nidx[sl][mi][0] = idx[(size_t)gm * S + step];
                }
            }
        }
    };
    auto loadA = [&](int step, int mi, int ks) {
        if constexpr (GATHER) {
            int node = nidx[step & 1][mi][(ks * IPS) / 4];
            int koff = (ks * 16 + kh * 8) % CIN;
            afr[mi][ks] = *(const bf16x8*)&hin[(size_t)node * CIN + koff];
        } else {
            int gm = m0 + wr * WM + mi * 32 + ml;
            if (gm >= N) gm = N - 1;
            afr[mi][ks] = *(const bf16x8*)&hin[(size_t)gm * K + step * 64 + ks * 16 + kh * 8];
        }
    };

    f32x16 acc[MT][NT];
#pragma unroll
    for (int mi = 0; mi < MT; ++mi)
#pragma unroll
        for (int ni = 0; ni < NT; ++ni) {
            f32x16 z = {};
            acc[mi][ni] = z;
        }

    // ---- init: B[0] (and B[1] if NSTEP==2), idx[0..1], A[0]
    stageB(0, 0);
    if constexpr (NSTEP == 2) stageB(1, 1);
    loadIdx(0);
#pragma unroll
    for (int mi = 0; mi < MT; ++mi)
#pragma unroll
        for (int ks = 0; ks < 4; ++ks) loadA(0, mi, ks);
    loadIdx(1);
    __syncthreads();

    for (int step = 0; step < NSTEP; ++step) {
        const bool more = (step + 1 < NSTEP);
        if (more && NSTEP > 2) stageB(step + 1, (step + 1) & 1);  // DMA in flight during MFMAs
        loadIdx(step + 2);                                        // depth-2 idx prefetch
#pragma unroll
        for (int ks = 0; ks < 4; ++ks) {
            const int cb = ks * 2 + kh;        // 16B chunk within the 64-wide step
            bf16x8 bfr[NT];
#pragma unroll
            for (int ni = 0; ni < NT; ++ni) {
                int col = wc * WN + ni * 32 + ml;
                bfr[ni] = *(const bf16x8*)&Bs[step & 1][cb * COUT + col];
            }
#pragma unroll
            for (int mi = 0; mi < MT; ++mi)
#pragma unroll
                for (int ni = 0; ni < NT; ++ni)
                    acc[mi][ni] = __builtin_amdgcn_mfma_f32_32x32x16_bf16(afr[mi][ks], bfr[ni], acc[mi][ni], 0, 0, 0);
            if (more) {
#pragma unroll
                for (int mi = 0; mi < MT; ++mi) loadA(step + 1, mi, ks);  // next step's A
            }
        }
        if (more && NSTEP > 2) __syncthreads();
    }

    // ---- epilogue: bias + ELU + bf16 store
#pragma unroll
    for (int ni = 0; ni < NT; ++ni) {
        const int colg = wc * WN + ni * 32 + ml;
        const float bv = bias[colg];
#pragma unroll
        for (int mi = 0; mi < MT; ++mi) {
#pragma unroll
            for (int r = 0; r < 16; ++r) {
                int mrow = wr * WM + mi * 32 + ((r & 3) + 8 * (r >> 2) + 4 * kh);
                int gm = m0 + mrow;
                if (gm < N)
                    hout[(size_t)gm * COUT + colg] = (__bf16)elu_f(acc[mi][ni][r] + bv);
            }
        }
    }
}

// ---------------------------------------------------------------- fc2 + log_softmax: [N,256] bf16 -> [N,12] f32
__global__ __launch_bounds__(256) void fc2_kernel(const __bf16* __restrict__ h4,
                                                  const __bf16* __restrict__ Wb,  // [12,256] bf16
                                                  const float* __restrict__ bias,
                                                  float* __restrict__ out, int N)
{
    const int lane = threadIdx.x & 63;
    const int w = threadIdx.x >> 6;
    const int c = lane & 31;   // k-chunk (8 bf16 each)
    const int half = lane >> 5;

    bf16x8 wreg[12];
#pragma unroll
    for (int o = 0; o < 12; ++o)
        wreg[o] = *(const bf16x8*)&Wb[o * 256 + c * 8];

    const int base = blockIdx.x * 32 + w * 8;
#pragma unroll
    for (int p = 0; p < 4; ++p) {
        int n = base + p * 2 + half;
        bool valid = n < N;
        int nn = valid ? n : N - 1;
        bf16x8 h = *(const bf16x8*)&h4[(size_t)nn * 256 + c * 8];
        float hf[8];
#pragma unroll
        for (int j = 0; j < 8; ++j) hf[j] = (float)h[j];
        float pr[12];
#pragma unroll
        for (int o = 0; o < 12; ++o) {
            float s = 0.f;
#pragma unroll
            for (int j = 0; j < 8; ++j) s += hf[j] * (float)wreg[o][j];
            pr[o] = s;
        }
#pragma unroll
        for (int off = 16; off > 0; off >>= 1) {
#pragma unroll
            for (int o = 0; o < 12; ++o) pr[o] += __shfl_down(pr[o], off, 32);
        }
        if (c == 0 && valid) {
            float logits[12], mx = -1e30f;
#pragma unroll
            for (int o = 0; o < 12; ++o) {
                logits[o] = pr[o] + bias[o];
                mx = fmaxf(mx, logits[o]);
            }
            float s = 0.f;
#pragma unroll
            for (int o = 0; o < 12; ++o) s += expf(logits[o] - mx);
            float lse = mx + logf(s);
#pragma unroll
            for (int o = 0; o < 12; ++o) out[(size_t)n * 12 + o] = logits[o] - lse;
        }
    }
}

extern "C" void kernel_launch(void* const* d_in, const int* in_sizes, int n_in,
                              void* d_out, int out_size, void* d_ws, size_t ws_size,
                              hipStream_t stream)
{
    const int N = 100000;
    const float* x     = (const float*)d_in[0];
    const int*   idx   = (const int*)  d_in[1];
    const float* fc0_w = (const float*)d_in[2];
    const float* fc0_b = (const float*)d_in[3];
    const float* w1    = (const float*)d_in[4];
    const float* b1    = (const float*)d_in[5];
    const float* w2    = (const float*)d_in[6];
    const float* b2    = (const float*)d_in[7];
    const float* w3    = (const float*)d_in[8];
    const float* b3    = (const float*)d_in[9];
    const float* fc1_w = (const float*)d_in[10];
    const float* fc1_b = (const float*)d_in[11];
    const float* fc2_w = (const float*)d_in[12];
    const float* fc2_b = (const float*)d_in[13];
    float* out = (float*)d_out;

    // ---- workspace layout (bf16 everywhere), ~100 MB total
    char* ws = (char*)d_ws;
    const int n_w1 = 32 * 256, n_w2 = 64 * 512, n_w3 = 128 * 1024, n_fc1 = 256 * 128, n_fc2 = 12 * 256;
    const int n_wb = n_w1 + n_w2 + n_w3 + n_fc1 + n_fc2;
    __bf16* wb  = (__bf16*)ws;
    __bf16* w1b = wb;
    __bf16* w2b = w1b + n_w1;
    __bf16* w3b = w2b + n_w2;
    __bf16* f1b = w3b + n_w3;
    __bf16* f2b = f1b + n_fc1;
    size_t off = ((size_t)n_wb * 2 + 4095) & ~(size_t)4095;
    __bf16* h0 = (__bf16*)(ws + off);  off += (size_t)N * 16 * 2;
    __bf16* h1 = (__bf16*)(ws + off);  off += (size_t)N * 32 * 2;
    __bf16* h2 = (__bf16*)(ws + off);  off += (size_t)N * 64 * 2;
    __bf16* h3 = (__bf16*)(ws + off);  off += (size_t)N * 128 * 2;
    __bf16* h4 = (__bf16*)(ws + off);  off += (size_t)N * 256 * 2;

    cvt5_kernel<<<(n_wb + 255) / 256, 256, 0, stream>>>(w1, n_w1, w2, n_w2, w3, n_w3,
                                                        fc1_w, n_fc1, fc2_w, n_fc2, wb);
    fc0_kernel<<<(N + 255) / 256, 256, 0, stream>>>(x, fc0_w, fc0_b, h0, N);
    // spiral1: 16ch x16 -> 32   (wave tile 32x32, ~60 VGPR -> 6 waves/EU)
    mfma_layer<16, 16, 32, 128, 4, 1, true, 6><<<(N + 127) / 128, 256, 0, stream>>>(h0, idx, w1b, b1, h1, N);
    // spiral2: 32ch x16 -> 64   (wave tile 64x32, ~92 VGPR -> 5 waves/EU)
    mfma_layer<32, 16, 64, 128, 2, 2, true, 5><<<(N + 127) / 128, 256, 0, stream>>>(h1, idx, w2b, b2, h2, N);
    // spiral3: 64ch x16 -> 128  (wave tile 64x64, ~120 VGPR -> 4 waves/EU)
    mfma_layer<64, 16, 128, 128, 2, 2, true, 4><<<(N + 127) / 128, 256, 0, stream>>>(h2, idx, w3b, b3, h3, N);
    // fc1: dense 128 -> 256     (wave tile 64x64, 2 steps, no in-loop barriers)
    mfma_layer<128, 1, 256, 64, 1, 4, false, 4><<<(N + 63) / 64, 256, 0, stream>>>(h3, nullptr, f1b, fc1_b, h4, N);
    // fc2 + log_softmax
    fc2_kernel<<<(N + 31) / 32, 256, 0, stream>>>(h4, f2b, fc2_b, out, N);
}

// Round 5
// 358.261 us; speedup vs baseline: 1.1945x; 1.1839x over previous
//
#include <hip/hip_runtime.h>
#include <math.h>

// N = 100000 nodes, SEQ = 16, layers: 3 ->16 ->32 ->64 ->128 ->256 ->12(log_softmax)
// bf16 MFMA path:
//   A (gathered) global->VGPR (16B frags), prefetched one step ahead, idx pre-transposed
//   to idxT[s][n] so idx loads are coalesced.
//   B staged to LDS via global_load_lds DMA (zero VGPR), k-major chunks -> conflict-free
//   ds_read_b128. NBUF template: stage-all (no in-loop barriers) / 4-deep (barrier per
//   2 steps) / 2-deep (barrier per step).
//   Epilogue: acc -> LDS (aliases B buffer) -> coalesced int4 global stores.

typedef __bf16 bf16x8 __attribute__((ext_vector_type(8)));
typedef float f32x16 __attribute__((ext_vector_type(16)));

__device__ __forceinline__ float elu_f(float v) { return v > 0.f ? v : expm1f(v); }

// ------------------------------------------------ fused fp32 -> bf16 weight conversion
__global__ __launch_bounds__(256) void cvt5_kernel(const float* __restrict__ a, int na,
                                                   const float* __restrict__ b, int nb,
                                                   const float* __restrict__ c, int nc,
                                                   const float* __restrict__ d, int nd,
                                                   const float* __restrict__ e, int ne,
                                                   __bf16* __restrict__ dst)
{
    int i = blockIdx.x * 256 + threadIdx.x;
    int t01 = na + nb, t02 = t01 + nc, t03 = t02 + nd, t04 = t03 + ne;
    if (i >= t04) return;
    float v;
    if (i < na)       v = a[i];
    else if (i < t01) v = b[i - na];
    else if (i < t02) v = c[i - t01];
    else if (i < t03) v = d[i - t02];
    else              v = e[i - t03];
    dst[i] = (__bf16)v;
}

// ------------------------------------------------ idx transpose: idxT[s*N + n] = idx[n*16 + s]
__global__ __launch_bounds__(256) void idxT_kernel(const int* __restrict__ idx,
                                                   int* __restrict__ idxT, int N)
{
    int i = blockIdx.x * 256 + threadIdx.x;
    if (i >= N * 16) return;
    int n = i >> 4, s = i & 15;
    idxT[s * N + n] = idx[i];
}

// ---------------------------------------------------------------- fc0: [N,3] -> [N,16] bf16
__global__ __launch_bounds__(256) void fc0_kernel(const float* __restrict__ x,
                                                  const float* __restrict__ w,
                                                  const float* __restrict__ b,
                                                  __bf16* __restrict__ h0, int N)
{
    int n = blockIdx.x * 256 + threadIdx.x;
    if (n >= N) return;
    float x0 = x[n * 3 + 0], x1 = x[n * 3 + 1], x2 = x[n * 3 + 2];
    __bf16 ob[16];
#pragma unroll
    for (int j = 0; j < 16; ++j)
        ob[j] = (__bf16)elu_f(w[j * 3 + 0] * x0 + w[j * 3 + 1] * x1 + w[j * 3 + 2] * x2 + b[j]);
    int4* dst = (int4*)&h0[(size_t)n * 16];
    dst[0] = *(int4*)&ob[0];
    dst[1] = *(int4*)&ob[8];
}

// ------------------------------------------- MFMA gather-GEMM
// out[n, col0+o] = elu( sum_k A[n,k] * W[col0+o][k] + bias[col0+o] )
// A[n, s*CIN+c] = hin[idxT[s][n], c]  (GATHER) or hin[n,k] (dense)
template <int CIN, int S, int COUT_B, int COUT_TOT, int TILE_M, int RW, int CW,
          bool GATHER, int NBUF, int MINW>
__global__ __launch_bounds__(256, MINW) void mfma_layer(const __bf16* __restrict__ hin,
                                                        const int* __restrict__ idxT,
                                                        const __bf16* __restrict__ Wb,
                                                        const float* __restrict__ bias,
                                                        __bf16* __restrict__ hout, int N)
{
    constexpr int K = CIN * S;
    constexpr int NSTEP = K / 64;
    static_assert(K % 64 == 0, "K%64");
    constexpr int WM = TILE_M / RW;
    constexpr int WN = COUT_B / CW;
    constexpr int MT = WM / 32;
    constexpr int NT = WN / 32;
    constexpr int IPS = GATHER ? (64 / CIN) : 1;     // neighbors covered per 64-wide k-step
    constexpr int CPT = (COUT_B * 8) / 256;          // B 16B chunks per thread per step
    static_assert(RW * CW == 4, "4 waves");
    static_assert(WM % 32 == 0 && WN % 32 == 0, "tile mult of 32");
    static_assert(NBUF == NSTEP || NBUF == 4 || NBUF == 2, "NBUF scheme");

    constexpr int LDC = COUT_B + 8;                  // padded bf16 leading dim for C staging
    constexpr int BS_BYTES = NBUF * COUT_B * 8 * 16;
    constexpr int CS_BYTES = TILE_M * LDC * 2;
    constexpr int SH = BS_BYTES > CS_BYTES ? BS_BYTES : CS_BYTES;
    __shared__ __align__(16) char smem[SH];
    int4* Bs = (int4*)smem;                          // [NBUF][COUT_B*8] k-major 16B chunks
    __bf16* Cs = (__bf16*)smem;                      // [TILE_M][LDC]

    const int tid = threadIdx.x;
    const int lane = tid & 63;
    const int w = tid >> 6;
    const int wr = w / CW;
    const int wc = w % CW;
    const int ml = lane & 31;
    const int kh = lane >> 5;
    const int m0 = blockIdx.x * TILE_M;
    const int col0 = blockIdx.y * COUT_B;

    auto stageB = [&](int step) {
        const int buf = step % NBUF;
#pragma unroll
        for (int c = 0; c < CPT; ++c) {
            int L = tid + c * 256;
            int k8 = L / COUT_B;
            int n = L % COUT_B;
            const __bf16* src = Wb + (size_t)(n + col0) * K + step * 64 + k8 * 8;
            __builtin_amdgcn_global_load_lds(
                (const __attribute__((address_space(1))) void*)src,
                (__attribute__((address_space(3))) void*)&Bs[buf * COUT_B * 8 + L],
                16, 0, 0);
        }
    };

    bf16x8 afr[2][MT][4];
    int nidx[2][MT][IPS];
    auto loadIdx = [&](int step) {
        if constexpr (GATHER) {
            if (step >= NSTEP) return;
            const int sl = step & 1;
#pragma unroll
            for (int mi = 0; mi < MT; ++mi) {
                int gm = m0 + wr * WM + mi * 32 + ml;
                if (gm >= N) gm = N - 1;
#pragma unroll
                for (int j = 0; j < IPS; ++j)
                    nidx[sl][mi][j] = idxT[(size_t)(step * IPS + j) * N + gm];
            }
        }
    };
    auto loadAstep = [&](int step) {
        if (step >= NSTEP) return;
        const int sl = step & 1;
#pragma unroll
        for (int mi = 0; mi < MT; ++mi) {
#pragma unroll
            for (int ks = 0; ks < 4; ++ks) {
                if constexpr (GATHER) {
                    int node = nidx[sl][mi][(ks * IPS) / 4];
                    int koff = (ks * 16 + kh * 8) % CIN;
                    afr[sl][mi][ks] = *(const bf16x8*)&hin[(size_t)node * CIN + koff];
                } else {
                    int gm = m0 + wr * WM + mi * 32 + ml;
                    if (gm >= N) gm = N - 1;
                    afr[sl][mi][ks] = *(const bf16x8*)&hin[(size_t)gm * K + step * 64 + ks * 16 + kh * 8];
                }
            }
        }
    };

    f32x16 acc[MT][NT];
#pragma unroll
    for (int mi = 0; mi < MT; ++mi)
#pragma unroll
        for (int ni = 0; ni < NT; ++ni) {
            f32x16 z = {};
            acc[mi][ni] = z;
        }

    auto compute = [&](int step) {
        const int buf = step % NBUF;
        const int sl = step & 1;
#pragma unroll
        for (int ks = 0; ks < 4; ++ks) {
            const int cb = ks * 2 + kh;
            bf16x8 bfr[NT];
#pragma unroll
            for (int ni = 0; ni < NT; ++ni)
                bfr[ni] = *(const bf16x8*)&Bs[buf * COUT_B * 8 + cb * COUT_B + wc * WN + ni * 32 + ml];
#pragma unroll
            for (int mi = 0; mi < MT; ++mi)
#pragma unroll
                for (int ni = 0; ni < NT; ++ni)
                    acc[mi][ni] = __builtin_amdgcn_mfma_f32_32x32x16_bf16(afr[sl][mi][ks], bfr[ni], acc[mi][ni], 0, 0, 0);
        }
    };

    // ---- prologue
#pragma unroll
    for (int s = 0; s < NBUF && s < NSTEP; ++s) stageB(s);
    loadIdx(0);
    loadIdx(1);
    loadAstep(0);
    __syncthreads();

    if constexpr (NSTEP <= NBUF) {
        // all B resident: zero in-loop barriers
#pragma unroll
        for (int s = 0; s < NSTEP; ++s) {
            compute(s);
            loadAstep(s + 1);
            loadIdx(s + 2);
        }
    } else if constexpr (NBUF == 4) {
        // barrier every 2 steps; stage 2..3 ahead
        for (int g = 0; g < NSTEP; g += 2) {
            if (g > 0) __syncthreads();
            if (g + 2 < NSTEP) stageB(g + 2);
            if (g + 3 < NSTEP) stageB(g + 3);
            compute(g);
            loadAstep(g + 1);
            loadIdx(g + 2);
            compute(g + 1);
            loadAstep(g + 2);
            loadIdx(g + 3);
        }
    } else {
        // NBUF==2: barrier every step, stage 1 ahead
        for (int s = 0; s < NSTEP; ++s) {
            const bool more = s + 1 < NSTEP;
            if (more) stageB(s + 1);
            compute(s);
            loadAstep(s + 1);
            loadIdx(s + 2);
            if (more) __syncthreads();
        }
    }

    // ---- epilogue: acc -> Cs (aliases Bs) -> coalesced stores
    __syncthreads();
#pragma unroll
    for (int ni = 0; ni < NT; ++ni) {
        const int col = wc * WN + ni * 32 + ml;
        const float bv = bias[col0 + col];
#pragma unroll
        for (int mi = 0; mi < MT; ++mi) {
#pragma unroll
            for (int r = 0; r < 16; ++r) {
                int row = wr * WM + mi * 32 + ((r & 3) + 8 * (r >> 2) + 4 * kh);
                Cs[row * LDC + col] = (__bf16)elu_f(acc[mi][ni][r] + bv);
            }
        }
    }
    __syncthreads();
    constexpr int C8 = COUT_B / 8;
#pragma unroll
    for (int j = tid; j < TILE_M * C8; j += 256) {
        int row = j / C8, c8 = j % C8;
        int gm = m0 + row;
        if (gm < N)
            *(int4*)&hout[(size_t)gm * COUT_TOT + col0 + c8 * 8] = *(int4*)&Cs[row * LDC + c8 * 8];
    }
}

// ---------------------------------------------------------------- fc2 + log_softmax: [N,256] bf16 -> [N,12] f32
__global__ __launch_bounds__(256) void fc2_kernel(const __bf16* __restrict__ h4,
                                                  const __bf16* __restrict__ Wb,  // [12,256] bf16
                                                  const float* __restrict__ bias,
                                                  float* __restrict__ out, int N)
{
    const int lane = threadIdx.x & 63;
    const int w = threadIdx.x >> 6;
    const int c = lane & 31;   // k-chunk (8 bf16 each)
    const int half = lane >> 5;

    bf16x8 wreg[12];
#pragma unroll
    for (int o = 0; o < 12; ++o)
        wreg[o] = *(const bf16x8*)&Wb[o * 256 + c * 8];

    const int base = blockIdx.x * 32 + w * 8;
#pragma unroll
    for (int p = 0; p < 4; ++p) {
        int n = base + p * 2 + half;
        bool valid = n < N;
        int nn = valid ? n : N - 1;
        bf16x8 h = *(const bf16x8*)&h4[(size_t)nn * 256 + c * 8];
        float hf[8];
#pragma unroll
        for (int j = 0; j < 8; ++j) hf[j] = (float)h[j];
        float pr[12];
#pragma unroll
        for (int o = 0; o < 12; ++o) {
            float s = 0.f;
#pragma unroll
            for (int j = 0; j < 8; ++j) s += hf[j] * (float)wreg[o][j];
            pr[o] = s;
        }
#pragma unroll
        for (int off = 16; off > 0; off >>= 1) {
#pragma unroll
            for (int o = 0; o < 12; ++o) pr[o] += __shfl_down(pr[o], off, 32);
        }
        if (c == 0 && valid) {
            float logits[12], mx = -1e30f;
#pragma unroll
            for (int o = 0; o < 12; ++o) {
                logits[o] = pr[o] + bias[o];
                mx = fmaxf(mx, logits[o]);
            }
            float s = 0.f;
#pragma unroll
            for (int o = 0; o < 12; ++o) s += expf(logits[o] - mx);
            float lse = mx + logf(s);
#pragma unroll
            for (int o = 0; o < 12; ++o) out[(size_t)n * 12 + o] = logits[o] - lse;
        }
    }
}

extern "C" void kernel_launch(void* const* d_in, const int* in_sizes, int n_in,
                              void* d_out, int out_size, void* d_ws, size_t ws_size,
                              hipStream_t stream)
{
    const int N = 100000;
    const float* x     = (const float*)d_in[0];
    const int*   idx   = (const int*)  d_in[1];
    const float* fc0_w = (const float*)d_in[2];
    const float* fc0_b = (const float*)d_in[3];
    const float* w1    = (const float*)d_in[4];
    const float* b1    = (const float*)d_in[5];
    const float* w2    = (const float*)d_in[6];
    const float* b2    = (const float*)d_in[7];
    const float* w3    = (const float*)d_in[8];
    const float* b3    = (const float*)d_in[9];
    const float* fc1_w = (const float*)d_in[10];
    const float* fc1_b = (const float*)d_in[11];
    const float* fc2_w = (const float*)d_in[12];
    const float* fc2_b = (const float*)d_in[13];
    float* out = (float*)d_out;

    // ---- workspace layout
    char* ws = (char*)d_ws;
    const int n_w1 = 32 * 256, n_w2 = 64 * 512, n_w3 = 128 * 1024, n_fc1 = 256 * 128, n_fc2 = 12 * 256;
    const int n_wb = n_w1 + n_w2 + n_w3 + n_fc1 + n_fc2;
    __bf16* wb  = (__bf16*)ws;
    __bf16* w1b = wb;
    __bf16* w2b = w1b + n_w1;
    __bf16* w3b = w2b + n_w2;
    __bf16* f1b = w3b + n_w3;
    __bf16* f2b = f1b + n_fc1;
    size_t off = ((size_t)n_wb * 2 + 4095) & ~(size_t)4095;
    int* idxT = (int*)(ws + off);      off += (size_t)N * 16 * 4;
    __bf16* h0 = (__bf16*)(ws + off);  off += (size_t)N * 16 * 2;
    __bf16* h1 = (__bf16*)(ws + off);  off += (size_t)N * 32 * 2;
    __bf16* h2 = (__bf16*)(ws + off);  off += (size_t)N * 64 * 2;
    __bf16* h3 = (__bf16*)(ws + off);  off += (size_t)N * 128 * 2;
    __bf16* h4 = (__bf16*)(ws + off);  off += (size_t)N * 256 * 2;

    cvt5_kernel<<<(n_wb + 255) / 256, 256, 0, stream>>>(w1, n_w1, w2, n_w2, w3, n_w3,
                                                        fc1_w, n_fc1, fc2_w, n_fc2, wb);
    idxT_kernel<<<(N * 16 + 255) / 256, 256, 0, stream>>>(idx, idxT, N);
    fc0_kernel<<<(N + 255) / 256, 256, 0, stream>>>(x, fc0_w, fc0_b, h0, N);

    // spiral1: 16ch x16 -> 32. TILE 128, NSTEP=4 all-resident, no in-loop barriers.
    mfma_layer<16, 16, 32, 32, 128, 4, 1, true, 4, 5>
        <<<dim3((N + 127) / 128, 1), 256, 0, stream>>>(h0, idxT, w1b, b1, h1, N);
    // spiral2: 32ch x16 -> 64. TILE 64, 4-deep B, barrier per 2 steps.
    mfma_layer<32, 16, 64, 64, 64, 2, 2, true, 4, 5>
        <<<dim3((N + 63) / 64, 1), 256, 0, stream>>>(h1, idxT, w2b, b2, h2, N);
    // spiral3: 64ch x16 -> 128. TILE 64, 2-deep B, barrier per step.
    mfma_layer<64, 16, 128, 128, 64, 2, 2, true, 2, 5>
        <<<dim3((N + 63) / 64, 1), 256, 0, stream>>>(h2, idxT, w3b, b3, h3, N);
    // fc1: dense 128 -> 256, split into 2 column-blocks of 128. NSTEP=2 all-resident.
    mfma_layer<128, 1, 128, 256, 64, 2, 2, false, 2, 5>
        <<<dim3((N + 63) / 64, 2), 256, 0, stream>>>(h3, nullptr, f1b, fc1_b, h4, N);
    // fc2 + log_softmax
    fc2_kernel<<<(N + 31) / 32, 256, 0, stream>>>(h4, f2b, fc2_b, out, N);
}

// Round 6
// 321.007 us; speedup vs baseline: 1.3332x; 1.1161x over previous
//
#include <hip/hip_runtime.h>
#include <math.h>

// N = 100000 nodes, SEQ = 16, layers: 3 ->16 ->32 ->64 ->128 ->256 ->12(log_softmax)
// Barrier-free bf16 MFMA main loop:
//   A (gathered) global->VGPR 16B frags, double-buffered, idx (pre-transposed) depth-2.
//   B read straight from global in MFMA fragment order (weights pre-swizzled by cvt
//   kernel) -> fully coalesced dwordx4, L2-resident, double-buffered in VGPRs.
//   NO __syncthreads in the K-loop, NO LDS in the K-loop -> no vmcnt(0) drains;
//   compiler emits fine-grained vmcnt(N) per use (AITER-style).
//   LDS used only for the coalesced C epilogue.

typedef __bf16 bf16x8 __attribute__((ext_vector_type(8)));
typedef float f32x16 __attribute__((ext_vector_type(16)));

__device__ __forceinline__ float elu_f(float v) { return v > 0.f ? v : expm1f(v); }

// ------------------------------------------------ weight prep: fp32 -> bf16, frag-major swizzle
// dst chunk ((k/64)*8 + (k%64)/8)*COUT + col, element k%8  <-  src[col*K + k]
template <int K, int C>
__device__ __forceinline__ void swz_one(const float* __restrict__ src, __bf16* __restrict__ dst, int j)
{
    int col = j / K;          // K is pow2
    int k = j & (K - 1);
    int chunk = ((k >> 6) * 8 + ((k & 63) >> 3)) * C + col;
    dst[chunk * 8 + (k & 7)] = (__bf16)src[j];
}

__global__ __launch_bounds__(256) void cvt_swz_kernel(const float* __restrict__ w1,
                                                      const float* __restrict__ w2,
                                                      const float* __restrict__ w3,
                                                      const float* __restrict__ f1,
                                                      const float* __restrict__ f2,
                                                      __bf16* __restrict__ d1,
                                                      __bf16* __restrict__ d2,
                                                      __bf16* __restrict__ d3,
                                                      __bf16* __restrict__ df1,
                                                      __bf16* __restrict__ df2)
{
    int i = blockIdx.x * 256 + threadIdx.x;
    if (i < 8192)        swz_one<256, 32>(w1, d1, i);
    else if (i < 40960)  swz_one<512, 64>(w2, d2, i - 8192);
    else if (i < 172032) swz_one<1024, 128>(w3, d3, i - 40960);
    else if (i < 204800) swz_one<128, 256>(f1, df1, i - 172032);
    else if (i < 207872) df2[i - 204800] = (__bf16)f2[i - 204800];   // fc2 stays row-major
}

// ------------------------------------------------ idx transpose: idxT[s*N + n] = idx[n*16 + s]
__global__ __launch_bounds__(256) void idxT_kernel(const int* __restrict__ idx,
                                                   int* __restrict__ idxT, int N)
{
    int i = blockIdx.x * 256 + threadIdx.x;
    if (i >= N * 16) return;
    int n = i >> 4, s = i & 15;
    idxT[s * N + n] = idx[i];
}

// ---------------------------------------------------------------- fc0: [N,3] -> [N,16] bf16
__global__ __launch_bounds__(256) void fc0_kernel(const float* __restrict__ x,
                                                  const float* __restrict__ w,
                                                  const float* __restrict__ b,
                                                  __bf16* __restrict__ h0, int N)
{
    int n = blockIdx.x * 256 + threadIdx.x;
    if (n >= N) return;
    float x0 = x[n * 3 + 0], x1 = x[n * 3 + 1], x2 = x[n * 3 + 2];
    __bf16 ob[16];
#pragma unroll
    for (int j = 0; j < 16; ++j)
        ob[j] = (__bf16)elu_f(w[j * 3 + 0] * x0 + w[j * 3 + 1] * x1 + w[j * 3 + 2] * x2 + b[j]);
    int4* dst = (int4*)&h0[(size_t)n * 16];
    dst[0] = *(int4*)&ob[0];
    dst[1] = *(int4*)&ob[8];
}

// ------------------------------------------- barrier-free MFMA gather-GEMM
// out[n, col0+o] = elu( sum_k A[n,k] * W[col0+o][k] + bias )
// A[n, s*CIN+c] = hin[idxT[s][n], c]  (GATHER) or hin[n,k] (dense)
template <int CIN, int S, int COUT_B, int COUT_TOT, int TILE_M, int RW, int CW,
          bool GATHER, int MINW>
__global__ __launch_bounds__(256, MINW) void mfma_layer(const __bf16* __restrict__ hin,
                                                        const int* __restrict__ idxT,
                                                        const __bf16* __restrict__ Wsw,
                                                        const float* __restrict__ bias,
                                                        __bf16* __restrict__ hout, int N)
{
    constexpr int K = CIN * S;
    constexpr int NSTEP = K / 64;
    static_assert(K % 64 == 0, "K%64");
    constexpr int WM = TILE_M / RW;
    constexpr int WN = COUT_B / CW;
    constexpr int MT = WM / 32;
    constexpr int NT = WN / 32;
    constexpr int IPS = GATHER ? (64 / CIN) : 1;   // neighbors per 64-wide k-step (>=1)
    static_assert(RW * CW == 4, "4 waves");
    static_assert(WM % 32 == 0 && WN % 32 == 0, "tile mult of 32");

    constexpr int LDC = COUT_B + 8;
    __shared__ __align__(16) __bf16 Cs[TILE_M][LDC];   // epilogue only

    const int tid = threadIdx.x;
    const int lane = tid & 63;
    const int w = tid >> 6;
    const int wr = w / CW;
    const int wc = w % CW;
    const int ml = lane & 31;
    const int kh = lane >> 5;
    const int m0 = blockIdx.x * TILE_M;
    const int col0 = blockIdx.y * COUT_B;

    bf16x8 afr[2][MT][4];
    bf16x8 bfr[2][NT][4];
    int nidx[2][MT][IPS];

    auto loadB = [&](int step) {
        const int sl = step & 1;
#pragma unroll
        for (int ni = 0; ni < NT; ++ni)
#pragma unroll
            for (int ks = 0; ks < 4; ++ks) {
                int cb = ks * 2 + kh;
                size_t chunk = (size_t)(step * 8 + cb) * COUT_TOT + col0 + wc * WN + ni * 32 + ml;
                bfr[sl][ni][ks] = *(const bf16x8*)&Wsw[chunk * 8];
            }
    };
    auto loadIdx = [&](int step) {
        if constexpr (GATHER) {
            if (step >= NSTEP) return;
            const int sl = step & 1;
#pragma unroll
            for (int mi = 0; mi < MT; ++mi) {
                int gm = m0 + wr * WM + mi * 32 + ml;
                if (gm >= N) gm = N - 1;
#pragma unroll
                for (int j = 0; j < IPS; ++j)
                    nidx[sl][mi][j] = idxT[(size_t)(step * IPS + j) * N + gm];
            }
        }
    };
    auto loadA = [&](int step) {
        if (step >= NSTEP) return;
        const int sl = step & 1;
#pragma unroll
        for (int mi = 0; mi < MT; ++mi) {
#pragma unroll
            for (int ks = 0; ks < 4; ++ks) {
                if constexpr (GATHER) {
                    int node = nidx[sl][mi][(ks * IPS) / 4];
                    int koff = (ks * 16 + kh * 8) % CIN;
                    afr[sl][mi][ks] = *(const bf16x8*)&hin[(size_t)node * CIN + koff];
                } else {
                    int gm = m0 + wr * WM + mi * 32 + ml;
                    if (gm >= N) gm = N - 1;
                    afr[sl][mi][ks] = *(const bf16x8*)&hin[(size_t)gm * K + step * 64 + ks * 16 + kh * 8];
                }
            }
        }
    };

    f32x16 acc[MT][NT];
#pragma unroll
    for (int mi = 0; mi < MT; ++mi)
#pragma unroll
        for (int ni = 0; ni < NT; ++ni) {
            f32x16 z = {};
            acc[mi][ni] = z;
        }

    // ---- prologue: everything for step 0, idx for step 1
    loadIdx(0);
    loadB(0);
    loadA(0);
    loadIdx(1);

    // ---- barrier-free K-loop (fully unrolled; reg-array indices compile-time)
#pragma unroll
    for (int s = 0; s < NSTEP; ++s) {
        if (s + 1 < NSTEP) {
            loadB(s + 1);
            loadA(s + 1);
            loadIdx(s + 2);
        }
        const int sl = s & 1;
#pragma unroll
        for (int ks = 0; ks < 4; ++ks)
#pragma unroll
            for (int mi = 0; mi < MT; ++mi)
#pragma unroll
                for (int ni = 0; ni < NT; ++ni)
                    acc[mi][ni] = __builtin_amdgcn_mfma_f32_32x32x16_bf16(
                        afr[sl][mi][ks], bfr[sl][ni][ks], acc[mi][ni], 0, 0, 0);
    }

    // ---- epilogue: acc -> LDS -> coalesced int4 stores
#pragma unroll
    for (int ni = 0; ni < NT; ++ni) {
        const int col = wc * WN + ni * 32 + ml;
        const float bv = bias[col0 + col];
#pragma unroll
        for (int mi = 0; mi < MT; ++mi) {
#pragma unroll
            for (int r = 0; r < 16; ++r) {
                int row = wr * WM + mi * 32 + ((r & 3) + 8 * (r >> 2) + 4 * kh);
                Cs[row][col] = (__bf16)elu_f(acc[mi][ni][r] + bv);
            }
        }
    }
    __syncthreads();
    constexpr int C8 = COUT_B / 8;
#pragma unroll
    for (int j = tid; j < TILE_M * C8; j += 256) {
        int row = j / C8, c8 = j % C8;
        int gm = m0 + row;
        if (gm < N)
            *(int4*)&hout[(size_t)gm * COUT_TOT + col0 + c8 * 8] = *(int4*)&Cs[row][c8 * 8];
    }
}

// ---------------------------------------------------------------- fc2 + log_softmax: [N,256] bf16 -> [N,12] f32
__global__ __launch_bounds__(256) void fc2_kernel(const __bf16* __restrict__ h4,
                                                  const __bf16* __restrict__ Wb,  // [12,256] bf16
                                                  const float* __restrict__ bias,
                                                  float* __restrict__ out, int N)
{
    const int lane = threadIdx.x & 63;
    const int w = threadIdx.x >> 6;
    const int c = lane & 31;
    const int half = lane >> 5;

    bf16x8 wreg[12];
#pragma unroll
    for (int o = 0; o < 12; ++o)
        wreg[o] = *(const bf16x8*)&Wb[o * 256 + c * 8];

    const int base = blockIdx.x * 32 + w * 8;
#pragma unroll
    for (int p = 0; p < 4; ++p) {
        int n = base + p * 2 + half;
        bool valid = n < N;
        int nn = valid ? n : N - 1;
        bf16x8 h = *(const bf16x8*)&h4[(size_t)nn * 256 + c * 8];
        float hf[8];
#pragma unroll
        for (int j = 0; j < 8; ++j) hf[j] = (float)h[j];
        float pr[12];
#pragma unroll
        for (int o = 0; o < 12; ++o) {
            float s = 0.f;
#pragma unroll
            for (int j = 0; j < 8; ++j) s += hf[j] * (float)wreg[o][j];
            pr[o] = s;
        }
#pragma unroll
        for (int off = 16; off > 0; off >>= 1) {
#pragma unroll
            for (int o = 0; o < 12; ++o) pr[o] += __shfl_down(pr[o], off, 32);
        }
        if (c == 0 && valid) {
            float logits[12], mx = -1e30f;
#pragma unroll
            for (int o = 0; o < 12; ++o) {
                logits[o] = pr[o] + bias[o];
                mx = fmaxf(mx, logits[o]);
            }
            float s = 0.f;
#pragma unroll
            for (int o = 0; o < 12; ++o) s += expf(logits[o] - mx);
            float lse = mx + logf(s);
#pragma unroll
            for (int o = 0; o < 12; ++o) out[(size_t)n * 12 + o] = logits[o] - lse;
        }
    }
}

extern "C" void kernel_launch(void* const* d_in, const int* in_sizes, int n_in,
                              void* d_out, int out_size, void* d_ws, size_t ws_size,
                              hipStream_t stream)
{
    const int N = 100000;
    const float* x     = (const float*)d_in[0];
    const int*   idx   = (const int*)  d_in[1];
    const float* fc0_w = (const float*)d_in[2];
    const float* fc0_b = (const float*)d_in[3];
    const float* w1    = (const float*)d_in[4];
    const float* b1    = (const float*)d_in[5];
    const float* w2    = (const float*)d_in[6];
    const float* b2    = (const float*)d_in[7];
    const float* w3    = (const float*)d_in[8];
    const float* b3    = (const float*)d_in[9];
    const float* fc1_w = (const float*)d_in[10];
    const float* fc1_b = (const float*)d_in[11];
    const float* fc2_w = (const float*)d_in[12];
    const float* fc2_b = (const float*)d_in[13];
    float* out = (float*)d_out;

    // ---- workspace layout
    char* ws = (char*)d_ws;
    const int n_w1 = 32 * 256, n_w2 = 64 * 512, n_w3 = 128 * 1024, n_fc1 = 256 * 128, n_fc2 = 12 * 256;
    const int n_wb = n_w1 + n_w2 + n_w3 + n_fc1 + n_fc2;   // 207872
    __bf16* w1b = (__bf16*)ws;
    __bf16* w2b = w1b + n_w1;
    __bf16* w3b = w2b + n_w2;
    __bf16* f1b = w3b + n_w3;
    __bf16* f2b = f1b + n_fc1;
    size_t off = ((size_t)n_wb * 2 + 4095) & ~(size_t)4095;
    int* idxT = (int*)(ws + off);      off += (size_t)N * 16 * 4;
    __bf16* h0 = (__bf16*)(ws + off);  off += (size_t)N * 16 * 2;
    __bf16* h1 = (__bf16*)(ws + off);  off += (size_t)N * 32 * 2;
    __bf16* h2 = (__bf16*)(ws + off);  off += (size_t)N * 64 * 2;
    __bf16* h3 = (__bf16*)(ws + off);  off += (size_t)N * 128 * 2;
    __bf16* h4 = (__bf16*)(ws + off);  off += (size_t)N * 256 * 2;

    cvt_swz_kernel<<<(n_wb + 255) / 256, 256, 0, stream>>>(w1, w2, w3, fc1_w, fc2_w,
                                                           w1b, w2b, w3b, f1b, f2b);
    idxT_kernel<<<(N * 16 + 255) / 256, 256, 0, stream>>>(idx, idxT, N);
    fc0_kernel<<<(N + 255) / 256, 256, 0, stream>>>(x, fc0_w, fc0_b, h0, N);

    // spiral1: 16ch x16 -> 32. TILE 128 (RW=4, CW=1), NSTEP=4.
    mfma_layer<16, 16, 32, 32, 128, 4, 1, true, 4>
        <<<dim3((N + 127) / 128, 1), 256, 0, stream>>>(h0, idxT, w1b, b1, h1, N);
    // spiral2: 32ch x16 -> 64. TILE 64 (RW=2, CW=2), NSTEP=8.
    mfma_layer<32, 16, 64, 64, 64, 2, 2, true, 4>
        <<<dim3((N + 63) / 64, 1), 256, 0, stream>>>(h1, idxT, w2b, b2, h2, N);
    // spiral3: 64ch x16 -> 128. TILE 64 (RW=2, CW=2), NSTEP=16.
    mfma_layer<64, 16, 128, 128, 64, 2, 2, true, 3>
        <<<dim3((N + 63) / 64, 1), 256, 0, stream>>>(h2, idxT, w3b, b3, h3, N);
    // fc1: dense 128 -> 256, 2 column-blocks of 128. NSTEP=2.
    mfma_layer<128, 1, 128, 256, 64, 2, 2, false, 3>
        <<<dim3((N + 63) / 64, 2), 256, 0, stream>>>(h3, nullptr, f1b, fc1_b, h4, N);
    // fc2 + log_softmax
    fc2_kernel<<<(N + 31) / 32, 256, 0, stream>>>(h4, f2b, fc2_b, out, N);
}

// Round 7
// 302.611 us; speedup vs baseline: 1.4142x; 1.0608x over previous
//
#include <hip/hip_runtime.h>
#include <math.h>

// N = 100000 nodes, SEQ = 16, layers: 3 ->16 ->32 ->64 ->128 ->256 ->12(log_softmax)
// Barrier-free bf16 MFMA main loop with ENFORCED software pipelining:
//   A (gathered) global->VGPR 16B frags, double-buffered; idx (pre-transposed) depth-2.
//   B read from global in MFMA fragment order (pre-swizzled weights, L2-resident),
//   double-buffered in VGPRs.
//   __builtin_amdgcn_sched_barrier(0) between the (s+1) load block and the (s) MFMA
//   block pins the pipeline: compiler cannot sink loads to their uses (R6 showed it
//   collapses the double-buffer to 32 VGPRs otherwise, serializing gather latency).
//   NO __syncthreads / NO LDS in the K-loop. LDS only for the coalesced C epilogue.

typedef __bf16 bf16x8 __attribute__((ext_vector_type(8)));
typedef float f32x16 __attribute__((ext_vector_type(16)));

__device__ __forceinline__ float elu_f(float v) { return v > 0.f ? v : expm1f(v); }

// ------------------------------------------------ weight prep: fp32 -> bf16, frag-major swizzle
// dst chunk ((k/64)*8 + (k%64)/8)*COUT + col, element k%8  <-  src[col*K + k]
template <int K, int C>
__device__ __forceinline__ void swz_one(const float* __restrict__ src, __bf16* __restrict__ dst, int j)
{
    int col = j / K;          // K is pow2
    int k = j & (K - 1);
    int chunk = ((k >> 6) * 8 + ((k & 63) >> 3)) * C + col;
    dst[chunk * 8 + (k & 7)] = (__bf16)src[j];
}

__global__ __launch_bounds__(256) void cvt_swz_kernel(const float* __restrict__ w1,
                                                      const float* __restrict__ w2,
                                                      const float* __restrict__ w3,
                                                      const float* __restrict__ f1,
                                                      const float* __restrict__ f2,
                                                      __bf16* __restrict__ d1,
                                                      __bf16* __restrict__ d2,
                                                      __bf16* __restrict__ d3,
                                                      __bf16* __restrict__ df1,
                                                      __bf16* __restrict__ df2)
{
    int i = blockIdx.x * 256 + threadIdx.x;
    if (i < 8192)        swz_one<256, 32>(w1, d1, i);
    else if (i < 40960)  swz_one<512, 64>(w2, d2, i - 8192);
    else if (i < 172032) swz_one<1024, 128>(w3, d3, i - 40960);
    else if (i < 204800) swz_one<128, 256>(f1, df1, i - 172032);
    else if (i < 207872) df2[i - 204800] = (__bf16)f2[i - 204800];   // fc2 stays row-major
}

// ------------------------------------------------ idx transpose: idxT[s*N + n] = idx[n*16 + s]
__global__ __launch_bounds__(256) void idxT_kernel(const int* __restrict__ idx,
                                                   int* __restrict__ idxT, int N)
{
    int i = blockIdx.x * 256 + threadIdx.x;
    if (i >= N * 16) return;
    int n = i >> 4, s = i & 15;
    idxT[s * N + n] = idx[i];
}

// ---------------------------------------------------------------- fc0: [N,3] -> [N,16] bf16
__global__ __launch_bounds__(256) void fc0_kernel(const float* __restrict__ x,
                                                  const float* __restrict__ w,
                                                  const float* __restrict__ b,
                                                  __bf16* __restrict__ h0, int N)
{
    int n = blockIdx.x * 256 + threadIdx.x;
    if (n >= N) return;
    float x0 = x[n * 3 + 0], x1 = x[n * 3 + 1], x2 = x[n * 3 + 2];
    __bf16 ob[16];
#pragma unroll
    for (int j = 0; j < 16; ++j)
        ob[j] = (__bf16)elu_f(w[j * 3 + 0] * x0 + w[j * 3 + 1] * x1 + w[j * 3 + 2] * x2 + b[j]);
    int4* dst = (int4*)&h0[(size_t)n * 16];
    dst[0] = *(int4*)&ob[0];
    dst[1] = *(int4*)&ob[8];
}

// ------------------------------------------- barrier-free, pipeline-pinned MFMA gather-GEMM
template <int CIN, int S, int COUT_B, int COUT_TOT, int TILE_M, int RW, int CW,
          bool GATHER, int MINW>
__global__ __launch_bounds__(256, MINW) void mfma_layer(const __bf16* __restrict__ hin,
                                                        const int* __restrict__ idxT,
                                                        const __bf16* __restrict__ Wsw,
                                                        const float* __restrict__ bias,
                                                        __bf16* __restrict__ hout, int N)
{
    constexpr int K = CIN * S;
    constexpr int NSTEP = K / 64;
    static_assert(K % 64 == 0, "K%64");
    constexpr int WM = TILE_M / RW;
    constexpr int WN = COUT_B / CW;
    constexpr int MT = WM / 32;
    constexpr int NT = WN / 32;
    constexpr int IPS = GATHER ? (64 / CIN) : 1;   // neighbors per 64-wide k-step (>=1)
    static_assert(RW * CW == 4, "4 waves");
    static_assert(WM % 32 == 0 && WN % 32 == 0, "tile mult of 32");

    constexpr int LDC = COUT_B + 8;
    __shared__ __align__(16) __bf16 Cs[TILE_M][LDC];   // epilogue only

    const int tid = threadIdx.x;
    const int lane = tid & 63;
    const int w = tid >> 6;
    const int wr = w / CW;
    const int wc = w % CW;
    const int ml = lane & 31;
    const int kh = lane >> 5;
    const int m0 = blockIdx.x * TILE_M;
    const int col0 = blockIdx.y * COUT_B;

    bf16x8 afr[2][MT][4];
    bf16x8 bfr[2][NT][4];
    int nidx[2][MT][IPS];

    auto loadB = [&](int step) {
        const int sl = step & 1;
#pragma unroll
        for (int ni = 0; ni < NT; ++ni)
#pragma unroll
            for (int ks = 0; ks < 4; ++ks) {
                int cb = ks * 2 + kh;
                size_t chunk = (size_t)(step * 8 + cb) * COUT_TOT + col0 + wc * WN + ni * 32 + ml;
                bfr[sl][ni][ks] = *(const bf16x8*)&Wsw[chunk * 8];
            }
    };
    auto loadIdx = [&](int step) {
        if constexpr (GATHER) {
            if (step >= NSTEP) return;
            const int sl = step & 1;
#pragma unroll
            for (int mi = 0; mi < MT; ++mi) {
                int gm = m0 + wr * WM + mi * 32 + ml;
                if (gm >= N) gm = N - 1;
#pragma unroll
                for (int j = 0; j < IPS; ++j)
                    nidx[sl][mi][j] = idxT[(size_t)(step * IPS + j) * N + gm];
            }
        }
    };
    auto loadA = [&](int step) {
        if (step >= NSTEP) return;
        const int sl = step & 1;
#pragma unroll
        for (int mi = 0; mi < MT; ++mi) {
#pragma unroll
            for (int ks = 0; ks < 4; ++ks) {
                if constexpr (GATHER) {
                    int node = nidx[sl][mi][(ks * IPS) / 4];
                    int koff = (ks * 16 + kh * 8) % CIN;
                    afr[sl][mi][ks] = *(const bf16x8*)&hin[(size_t)node * CIN + koff];
                } else {
                    int gm = m0 + wr * WM + mi * 32 + ml;
                    if (gm >= N) gm = N - 1;
                    afr[sl][mi][ks] = *(const bf16x8*)&hin[(size_t)gm * K + step * 64 + ks * 16 + kh * 8];
                }
            }
        }
    };

    f32x16 acc[MT][NT];
#pragma unroll
    for (int mi = 0; mi < MT; ++mi)
#pragma unroll
        for (int ni = 0; ni < NT; ++ni) {
            f32x16 z = {};
            acc[mi][ni] = z;
        }

    // ---- prologue: everything for step 0, idx for step 1
    loadIdx(0);
    loadB(0);
    loadA(0);
    loadIdx(1);

    // ---- pipeline-pinned K-loop (fully unrolled)
#pragma unroll
    for (int s = 0; s < NSTEP; ++s) {
        if (s + 1 < NSTEP) {
            loadB(s + 1);
            loadA(s + 1);
            loadIdx(s + 2);
        }
        // Fence: loads above may NOT sink below; MFMAs below may NOT hoist above.
        __builtin_amdgcn_sched_barrier(0);
        const int sl = s & 1;
#pragma unroll
        for (int ks = 0; ks < 4; ++ks)
#pragma unroll
            for (int mi = 0; mi < MT; ++mi)
#pragma unroll
                for (int ni = 0; ni < NT; ++ni)
                    acc[mi][ni] = __builtin_amdgcn_mfma_f32_32x32x16_bf16(
                        afr[sl][mi][ks], bfr[sl][ni][ks], acc[mi][ni], 0, 0, 0);
    }

    // ---- epilogue: acc -> LDS -> coalesced int4 stores
#pragma unroll
    for (int ni = 0; ni < NT; ++ni) {
        const int col = wc * WN + ni * 32 + ml;
        const float bv = bias[col0 + col];
#pragma unroll
        for (int mi = 0; mi < MT; ++mi) {
#pragma unroll
            for (int r = 0; r < 16; ++r) {
                int row = wr * WM + mi * 32 + ((r & 3) + 8 * (r >> 2) + 4 * kh);
                Cs[row][col] = (__bf16)elu_f(acc[mi][ni][r] + bv);
            }
        }
    }
    __syncthreads();
    constexpr int C8 = COUT_B / 8;
#pragma unroll
    for (int j = tid; j < TILE_M * C8; j += 256) {
        int row = j / C8, c8 = j % C8;
        int gm = m0 + row;
        if (gm < N)
            *(int4*)&hout[(size_t)gm * COUT_TOT + col0 + c8 * 8] = *(int4*)&Cs[row][c8 * 8];
    }
}

// ---------------------------------------------------------------- fc2 + log_softmax: [N,256] bf16 -> [N,12] f32
__global__ __launch_bounds__(256) void fc2_kernel(const __bf16* __restrict__ h4,
                                                  const __bf16* __restrict__ Wb,  // [12,256] bf16
                                                  const float* __restrict__ bias,
                                                  float* __restrict__ out, int N)
{
    const int lane = threadIdx.x & 63;
    const int w = threadIdx.x >> 6;
    const int c = lane & 31;
    const int half = lane >> 5;

    bf16x8 wreg[12];
#pragma unroll
    for (int o = 0; o < 12; ++o)
        wreg[o] = *(const bf16x8*)&Wb[o * 256 + c * 8];

    const int base = blockIdx.x * 32 + w * 8;
#pragma unroll
    for (int p = 0; p < 4; ++p) {
        int n = base + p * 2 + half;
        bool valid = n < N;
        int nn = valid ? n : N - 1;
        bf16x8 h = *(const bf16x8*)&h4[(size_t)nn * 256 + c * 8];
        float hf[8];
#pragma unroll
        for (int j = 0; j < 8; ++j) hf[j] = (float)h[j];
        float pr[12];
#pragma unroll
        for (int o = 0; o < 12; ++o) {
            float s = 0.f;
#pragma unroll
            for (int j = 0; j < 8; ++j) s += hf[j] * (float)wreg[o][j];
            pr[o] = s;
        }
#pragma unroll
        for (int off = 16; off > 0; off >>= 1) {
#pragma unroll
            for (int o = 0; o < 12; ++o) pr[o] += __shfl_down(pr[o], off, 32);
        }
        if (c == 0 && valid) {
            float logits[12], mx = -1e30f;
#pragma unroll
            for (int o = 0; o < 12; ++o) {
                logits[o] = pr[o] + bias[o];
                mx = fmaxf(mx, logits[o]);
            }
            float s = 0.f;
#pragma unroll
            for (int o = 0; o < 12; ++o) s += expf(logits[o] - mx);
            float lse = mx + logf(s);
#pragma unroll
            for (int o = 0; o < 12; ++o) out[(size_t)n * 12 + o] = logits[o] - lse;
        }
    }
}

extern "C" void kernel_launch(void* const* d_in, const int* in_sizes, int n_in,
                              void* d_out, int out_size, void* d_ws, size_t ws_size,
                              hipStream_t stream)
{
    const int N = 100000;
    const float* x     = (const float*)d_in[0];
    const int*   idx   = (const int*)  d_in[1];
    const float* fc0_w = (const float*)d_in[2];
    const float* fc0_b = (const float*)d_in[3];
    const float* w1    = (const float*)d_in[4];
    const float* b1    = (const float*)d_in[5];
    const float* w2    = (const float*)d_in[6];
    const float* b2    = (const float*)d_in[7];
    const float* w3    = (const float*)d_in[8];
    const float* b3    = (const float*)d_in[9];
    const float* fc1_w = (const float*)d_in[10];
    const float* fc1_b = (const float*)d_in[11];
    const float* fc2_w = (const float*)d_in[12];
    const float* fc2_b = (const float*)d_in[13];
    float* out = (float*)d_out;

    // ---- workspace layout
    char* ws = (char*)d_ws;
    const int n_w1 = 32 * 256, n_w2 = 64 * 512, n_w3 = 128 * 1024, n_fc1 = 256 * 128, n_fc2 = 12 * 256;
    const int n_wb = n_w1 + n_w2 + n_w3 + n_fc1 + n_fc2;   // 207872
    __bf16* w1b = (__bf16*)ws;
    __bf16* w2b = w1b + n_w1;
    __bf16* w3b = w2b + n_w2;
    __bf16* f1b = w3b + n_w3;
    __bf16* f2b = f1b + n_fc1;
    size_t off = ((size_t)n_wb * 2 + 4095) & ~(size_t)4095;
    int* idxT = (int*)(ws + off);      off += (size_t)N * 16 * 4;
    __bf16* h0 = (__bf16*)(ws + off);  off += (size_t)N * 16 * 2;
    __bf16* h1 = (__bf16*)(ws + off);  off += (size_t)N * 32 * 2;
    __bf16* h2 = (__bf16*)(ws + off);  off += (size_t)N * 64 * 2;
    __bf16* h3 = (__bf16*)(ws + off);  off += (size_t)N * 128 * 2;
    __bf16* h4 = (__bf16*)(ws + off);  off += (size_t)N * 256 * 2;

    cvt_swz_kernel<<<(n_wb + 255) / 256, 256, 0, stream>>>(w1, w2, w3, fc1_w, fc2_w,
                                                           w1b, w2b, w3b, f1b, f2b);
    idxT_kernel<<<(N * 16 + 255) / 256, 256, 0, stream>>>(idx, idxT, N);
    fc0_kernel<<<(N + 255) / 256, 256, 0, stream>>>(x, fc0_w, fc0_b, h0, N);

    // spiral1: 16ch x16 -> 32. TILE 128 (RW=4, CW=1), NSTEP=4.
    mfma_layer<16, 16, 32, 32, 128, 4, 1, true, 4>
        <<<dim3((N + 127) / 128, 1), 256, 0, stream>>>(h0, idxT, w1b, b1, h1, N);
    // spiral2: 32ch x16 -> 64. TILE 64 (RW=2, CW=2), NSTEP=8.
    mfma_layer<32, 16, 64, 64, 64, 2, 2, true, 4>
        <<<dim3((N + 63) / 64, 1), 256, 0, stream>>>(h1, idxT, w2b, b2, h2, N);
    // spiral3: 64ch x16 -> 128. TILE 64 (RW=2, CW=2), NSTEP=16.
    mfma_layer<64, 16, 128, 128, 64, 2, 2, true, 3>
        <<<dim3((N + 63) / 64, 1), 256, 0, stream>>>(h2, idxT, w3b, b3, h3, N);
    // fc1: dense 128 -> 256, 2 column-blocks of 128. NSTEP=2.
    mfma_layer<128, 1, 128, 256, 64, 2, 2, false, 3>
        <<<dim3((N + 63) / 64, 2), 256, 0, stream>>>(h3, nullptr, f1b, fc1_b, h4, N);
    // fc2 + log_softmax
    fc2_kernel<<<(N + 31) / 32, 256, 0, stream>>>(h4, f2b, fc2_b, out, N);
}

// Round 8
// 277.331 us; speedup vs baseline: 1.5431x; 1.0912x over previous
//
#include <hip/hip_runtime.h>
#include <math.h>
#include <utility>

// N = 100000 nodes, SEQ = 16, layers: 3 ->16 ->32 ->64 ->128 ->256 ->12(log_softmax)
// bf16 MFMA, barrier-free K-loop, gather staged via global_load_lds into PER-WAVE
// double-buffered LDS regions with manual fine-grained s_waitcnt vmcnt(N):
//   - A (gathered): global->LDS DMA (zero VGPR), chunk-XOR swizzle applied at the
//     source address so ds_read_b128 fragment reads are bank-conflict-free.
//   - idx: per-lane prefetch (depth 2) in exactly the DMA-lane layout.
//   - B: VGPR double-buffer from frag-major pre-swizzled weights (L2-resident).
//   - sched_barrier(0) fences pin group order so the vmcnt count is exact.
//   - NO __syncthreads in the K-loop (per-wave buffers). LDS reused for C epilogue.

typedef __bf16 bf16x8 __attribute__((ext_vector_type(8)));
typedef float f32x16 __attribute__((ext_vector_type(16)));

template <int V> using ic = std::integral_constant<int, V>;

template <typename F, int... Is>
__device__ __forceinline__ void static_for_impl(F&& f, std::integer_sequence<int, Is...>) {
    (f(ic<Is>{}), ...);
}
template <int N_, typename F>
__device__ __forceinline__ void static_for(F&& f) {
    static_for_impl(static_cast<F&&>(f), std::make_integer_sequence<int, N_>{});
}

template <int N_>
__device__ __forceinline__ void wait_vmcnt() {
    static_assert(N_ <= 63, "vmcnt range");
    // gfx9 encoding: vmcnt[3:0] | expcnt<<4 | lgkmcnt<<8 | vmcnt[5:4]<<14 (exp/lgkm = no-wait)
    __builtin_amdgcn_s_waitcnt((N_ & 0xF) | (0x7 << 4) | (0xF << 8) | ((N_ >> 4) << 14));
}

__device__ __forceinline__ float elu_f(float v) { return v > 0.f ? v : expm1f(v); }

// ------------------------------------------------ weight prep: fp32 -> bf16, frag-major swizzle
// dst chunk ((k/64)*8 + (k%64)/8)*COUT + col, element k%8  <-  src[col*K + k]
template <int K, int C>
__device__ __forceinline__ void swz_one(const float* __restrict__ src, __bf16* __restrict__ dst, int j)
{
    int col = j / K;          // K is pow2
    int k = j & (K - 1);
    int chunk = ((k >> 6) * 8 + ((k & 63) >> 3)) * C + col;
    dst[chunk * 8 + (k & 7)] = (__bf16)src[j];
}

__global__ __launch_bounds__(256) void cvt_swz_kernel(const float* __restrict__ w1,
                                                      const float* __restrict__ w2,
                                                      const float* __restrict__ w3,
                                                      const float* __restrict__ f1,
                                                      const float* __restrict__ f2,
                                                      __bf16* __restrict__ d1,
                                                      __bf16* __restrict__ d2,
                                                      __bf16* __restrict__ d3,
                                                      __bf16* __restrict__ df1,
                                                      __bf16* __restrict__ df2)
{
    int i = blockIdx.x * 256 + threadIdx.x;
    if (i < 8192)        swz_one<256, 32>(w1, d1, i);
    else if (i < 40960)  swz_one<512, 64>(w2, d2, i - 8192);
    else if (i < 172032) swz_one<1024, 128>(w3, d3, i - 40960);
    else if (i < 204800) swz_one<128, 256>(f1, df1, i - 172032);
    else if (i < 207872) df2[i - 204800] = (__bf16)f2[i - 204800];   // fc2 stays row-major
}

// ------------------------------------------------ idx transpose: idxT[s*N + n] = idx[n*16 + s]
__global__ __launch_bounds__(256) void idxT_kernel(const int* __restrict__ idx,
                                                   int* __restrict__ idxT, int N)
{
    int i = blockIdx.x * 256 + threadIdx.x;
    if (i >= N * 16) return;
    int n = i >> 4, s = i & 15;
    idxT[s * N + n] = idx[i];
}

// ---------------------------------------------------------------- fc0: [N,3] -> [N,16] bf16
__global__ __launch_bounds__(256) void fc0_kernel(const float* __restrict__ x,
                                                  const float* __restrict__ w,
                                                  const float* __restrict__ b,
                                                  __bf16* __restrict__ h0, int N)
{
    int n = blockIdx.x * 256 + threadIdx.x;
    if (n >= N) return;
    float x0 = x[n * 3 + 0], x1 = x[n * 3 + 1], x2 = x[n * 3 + 2];
    __bf16 ob[16];
#pragma unroll
    for (int j = 0; j < 16; ++j)
        ob[j] = (__bf16)elu_f(w[j * 3 + 0] * x0 + w[j * 3 + 1] * x1 + w[j * 3 + 2] * x2 + b[j]);
    int4* dst = (int4*)&h0[(size_t)n * 16];
    dst[0] = *(int4*)&ob[0];
    dst[1] = *(int4*)&ob[8];
}

// ------------------------------------------- barrier-free MFMA gather-GEMM, LDS-DMA A path
template <int CIN, int S, int COUT_B, int COUT_TOT, int TILE_M, int RW, int CW,
          bool GATHER, int MINW>
__global__ __launch_bounds__(256, MINW) void mfma_layer(const __bf16* __restrict__ hin,
                                                        const int* __restrict__ idxT,
                                                        const __bf16* __restrict__ Wsw,
                                                        const float* __restrict__ bias,
                                                        __bf16* __restrict__ hout, int N)
{
    constexpr int K = CIN * S;
    constexpr int NSTEP = K / 64;
    static_assert(K % 64 == 0, "K%64");
    constexpr int WM = TILE_M / RW;        // rows per wave
    constexpr int WN = COUT_B / CW;
    constexpr int NT = WN / 32;
    constexpr int IPS = GATHER ? (64 / CIN) : 1;
    constexpr int D = WM / 8;              // DMA insts per step per wave
    constexpr int Bn = NT * 4;             // B vmem loads per step
    constexpr int I = GATHER ? D : 0;      // idx vmem loads per step
    static_assert(RW * CW == 4, "4 waves");
    static_assert(WM == 32, "one 32-row subtile per wave");
    static_assert(WN % 32 == 0, "col tile");

    constexpr int ABYTES = 4 * 2 * WM * 128;              // 4 waves x 2 bufs x (WM x 64ch bf16)
    constexpr int CBYTES = TILE_M * (COUT_B + 8) * 2;
    constexpr int SH = ABYTES > CBYTES ? ABYTES : CBYTES;
    __shared__ __align__(16) char smem[SH];

    const int tid = threadIdx.x;
    const int lane = tid & 63;
    const int w = tid >> 6;
    const int wr = w / CW;
    const int wc = w % CW;
    const int ml = lane & 31;
    const int kh = lane >> 5;
    const int m0 = blockIdx.x * TILE_M;
    const int col0 = blockIdx.y * COUT_B;
    const int rbase = m0 + wr * WM;

    char* const Aw = smem + w * (2 * WM * 128);   // this wave's double buffer

    bf16x8 bfr[2][NT][4];
    int myIdx[2][GATHER ? D : 1];

    auto loadB = [&](auto stepc) {
        constexpr int step = decltype(stepc)::value;
        if constexpr (step < NSTEP) {
            constexpr int sl = step & 1;
#pragma unroll
            for (int ni = 0; ni < NT; ++ni)
#pragma unroll
                for (int ks = 0; ks < 4; ++ks) {
                    int cb = ks * 2 + kh;
                    size_t chunk = (size_t)(step * 8 + cb) * COUT_TOT + col0 + wc * WN + ni * 32 + ml;
                    bfr[sl][ni][ks] = *(const bf16x8*)&Wsw[chunk * 8];
                }
        }
    };

    // per-lane idx prefetch in DMA-lane layout: inst i, lane t -> row i*8+(t>>3), chunk (t&7)^(r&7)
    auto loadMyIdx = [&](auto stepc) {
        constexpr int step = decltype(stepc)::value;
        if constexpr (GATHER && step < NSTEP) {
            constexpr int sl = step & 1;
#pragma unroll
            for (int i = 0; i < D; ++i) {
                int r = i * 8 + (lane >> 3);
                int c = (lane & 7) ^ (r & 7);
                int j = (c * 8) / CIN;
                int gm = rbase + r; if (gm >= N) gm = N - 1;
                myIdx[sl][i] = idxT[(size_t)(step * IPS + j) * N + gm];
            }
        }
    };

    auto issueDMA = [&](auto stepc) {
        constexpr int step = decltype(stepc)::value;
        if constexpr (step < NSTEP) {
            constexpr int sl = step & 1;
            char* base = Aw + sl * (WM * 128);
#pragma unroll
            for (int i = 0; i < D; ++i) {
                int r = i * 8 + (lane >> 3);
                int c = (lane & 7) ^ (r & 7);
                const __bf16* src;
                if constexpr (GATHER) {
                    int koff = (c * 8) & (CIN - 1);
                    src = hin + (size_t)myIdx[sl][i] * CIN + koff;
                } else {
                    int gm = rbase + r; if (gm >= N) gm = N - 1;
                    src = hin + (size_t)gm * K + step * 64 + c * 8;
                }
                __builtin_amdgcn_global_load_lds(
                    (const __attribute__((address_space(1))) void*)src,
                    (__attribute__((address_space(3))) void*)(base + i * 1024),
                    16, 0, 0);
            }
        }
    };

    f32x16 acc[NT];
#pragma unroll
    for (int ni = 0; ni < NT; ++ni) { f32x16 z = {}; acc[ni] = z; }

    // ---- prologue: idx(0) -> DMA(0) | fence | B(0), idx(1)
    loadMyIdx(ic<0>{});
    issueDMA(ic<0>{});
    __builtin_amdgcn_sched_barrier(0);
    loadB(ic<0>{});
    loadMyIdx(ic<1>{});

    // ---- barrier-free K-loop, compile-time step index (exact vmcnt immediates)
    static_for<NSTEP>([&](auto sc) {
        constexpr int s = decltype(sc)::value;
        constexpr int sl = s & 1;
        if constexpr (s + 1 < NSTEP) {
            issueDMA(ic<s + 1>{});
            __builtin_amdgcn_sched_barrier(0);   // DMA group strictly first -> count exact
            loadB(ic<s + 1>{});
            loadMyIdx(ic<s + 2>{});
        }
        __builtin_amdgcn_sched_barrier(0);
        // ops issued after DMA(s)'s last inst:
        constexpr int WAITN = Bn + ((s + 1 < NSTEP) ? (I + D + Bn) : 0)
                                 + ((s + 2 < NSTEP) ? I : 0);
        wait_vmcnt<WAITN>();                      // A(s) now resident in LDS
        __builtin_amdgcn_sched_barrier(0);

        const char* base = Aw + sl * (WM * 128);
        bf16x8 afr[4];
#pragma unroll
        for (int ks = 0; ks < 4; ++ks) {
            int cb = ks * 2 + kh;
            int slot = ml * 8 + (cb ^ (ml & 7));
            afr[ks] = *(const bf16x8*)(base + slot * 16);
        }
#pragma unroll
        for (int ks = 0; ks < 4; ++ks)
#pragma unroll
            for (int ni = 0; ni < NT; ++ni)
                acc[ni] = __builtin_amdgcn_mfma_f32_32x32x16_bf16(afr[ks], bfr[sl][ni][ks], acc[ni], 0, 0, 0);
    });

    // ---- epilogue: acc -> LDS (reuse A region) -> coalesced int4 stores
    __syncthreads();
    __bf16* Cs = (__bf16*)smem;
    constexpr int LDC = COUT_B + 8;
#pragma unroll
    for (int ni = 0; ni < NT; ++ni) {
        const int col = wc * WN + ni * 32 + ml;
        const float bv = bias[col0 + col];
#pragma unroll
        for (int r = 0; r < 16; ++r) {
            int row = wr * WM + ((r & 3) + 8 * (r >> 2) + 4 * kh);
            Cs[row * LDC + col] = (__bf16)elu_f(acc[ni][r] + bv);
        }
    }
    __syncthreads();
    constexpr int C8 = COUT_B / 8;
#pragma unroll
    for (int j2 = tid; j2 < TILE_M * C8; j2 += 256) {
        int row = j2 / C8, c8 = j2 % C8;
        int gm = m0 + row;
        if (gm < N)
            *(int4*)&hout[(size_t)gm * COUT_TOT + col0 + c8 * 8] = *(int4*)&Cs[row * LDC + c8 * 8];
    }
}

// ---------------------------------------------------------------- fc2 + log_softmax: [N,256] bf16 -> [N,12] f32
__global__ __launch_bounds__(256) void fc2_kernel(const __bf16* __restrict__ h4,
                                                  const __bf16* __restrict__ Wb,  // [12,256] bf16
                                                  const float* __restrict__ bias,
                                                  float* __restrict__ out, int N)
{
    const int lane = threadIdx.x & 63;
    const int w = threadIdx.x >> 6;
    const int c = lane & 31;
    const int half = lane >> 5;

    bf16x8 wreg[12];
#pragma unroll
    for (int o = 0; o < 12; ++o)
        wreg[o] = *(const bf16x8*)&Wb[o * 256 + c * 8];

    const int base = blockIdx.x * 32 + w * 8;
#pragma unroll
    for (int p = 0; p < 4; ++p) {
        int n = base + p * 2 + half;
        bool valid = n < N;
        int nn = valid ? n : N - 1;
        bf16x8 h = *(const bf16x8*)&h4[(size_t)nn * 256 + c * 8];
        float hf[8];
#pragma unroll
        for (int j = 0; j < 8; ++j) hf[j] = (float)h[j];
        float pr[12];
#pragma unroll
        for (int o = 0; o < 12; ++o) {
            float s = 0.f;
#pragma unroll
            for (int j = 0; j < 8; ++j) s += hf[j] * (float)wreg[o][j];
            pr[o] = s;
        }
#pragma unroll
        for (int off = 16; off > 0; off >>= 1) {
#pragma unroll
            for (int o = 0; o < 12; ++o) pr[o] += __shfl_down(pr[o], off, 32);
        }
        if (c == 0 && valid) {
            float logits[12], mx = -1e30f;
#pragma unroll
            for (int o = 0; o < 12; ++o) {
                logits[o] = pr[o] + bias[o];
                mx = fmaxf(mx, logits[o]);
            }
            float s = 0.f;
#pragma unroll
            for (int o = 0; o < 12; ++o) s += expf(logits[o] - mx);
            float lse = mx + logf(s);
#pragma unroll
            for (int o = 0; o < 12; ++o) out[(size_t)n * 12 + o] = logits[o] - lse;
        }
    }
}

extern "C" void kernel_launch(void* const* d_in, const int* in_sizes, int n_in,
                              void* d_out, int out_size, void* d_ws, size_t ws_size,
                              hipStream_t stream)
{
    const int N = 100000;
    const float* x     = (const float*)d_in[0];
    const int*   idx   = (const int*)  d_in[1];
    const float* fc0_w = (const float*)d_in[2];
    const float* fc0_b = (const float*)d_in[3];
    const float* w1    = (const float*)d_in[4];
    const float* b1    = (const float*)d_in[5];
    const float* w2    = (const float*)d_in[6];
    const float* b2    = (const float*)d_in[7];
    const float* w3    = (const float*)d_in[8];
    const float* b3    = (const float*)d_in[9];
    const float* fc1_w = (const float*)d_in[10];
    const float* fc1_b = (const float*)d_in[11];
    const float* fc2_w = (const float*)d_in[12];
    const float* fc2_b = (const float*)d_in[13];
    float* out = (float*)d_out;

    // ---- workspace layout
    char* ws = (char*)d_ws;
    const int n_w1 = 32 * 256, n_w2 = 64 * 512, n_w3 = 128 * 1024, n_fc1 = 256 * 128, n_fc2 = 12 * 256;
    const int n_wb = n_w1 + n_w2 + n_w3 + n_fc1 + n_fc2;   // 207872
    __bf16* w1b = (__bf16*)ws;
    __bf16* w2b = w1b + n_w1;
    __bf16* w3b = w2b + n_w2;
    __bf16* f1b = w3b + n_w3;
    __bf16* f2b = f1b + n_fc1;
    size_t off = ((size_t)n_wb * 2 + 4095) & ~(size_t)4095;
    int* idxT = (int*)(ws + off);      off += (size_t)N * 16 * 4;
    __bf16* h0 = (__bf16*)(ws + off);  off += (size_t)N * 16 * 2;
    __bf16* h1 = (__bf16*)(ws + off);  off += (size_t)N * 32 * 2;
    __bf16* h2 = (__bf16*)(ws + off);  off += (size_t)N * 64 * 2;
    __bf16* h3 = (__bf16*)(ws + off);  off += (size_t)N * 128 * 2;
    __bf16* h4 = (__bf16*)(ws + off);  off += (size_t)N * 256 * 2;

    cvt_swz_kernel<<<(n_wb + 255) / 256, 256, 0, stream>>>(w1, w2, w3, fc1_w, fc2_w,
                                                           w1b, w2b, w3b, f1b, f2b);
    idxT_kernel<<<(N * 16 + 255) / 256, 256, 0, stream>>>(idx, idxT, N);
    fc0_kernel<<<(N + 255) / 256, 256, 0, stream>>>(x, fc0_w, fc0_b, h0, N);

    // spiral1: 16ch x16 -> 32. TILE 128 (RW=4, CW=1), NSTEP=4.
    mfma_layer<16, 16, 32, 32, 128, 4, 1, true, 4>
        <<<dim3((N + 127) / 128, 1), 256, 0, stream>>>(h0, idxT, w1b, b1, h1, N);
    // spiral2: 32ch x16 -> 64. TILE 64 (RW=2, CW=2), NSTEP=8.
    mfma_layer<32, 16, 64, 64, 64, 2, 2, true, 4>
        <<<dim3((N + 63) / 64, 1), 256, 0, stream>>>(h1, idxT, w2b, b2, h2, N);
    // spiral3: 64ch x16 -> 128. TILE 64 (RW=2, CW=2), NSTEP=16.
    mfma_layer<64, 16, 128, 128, 64, 2, 2, true, 3>
        <<<dim3((N + 63) / 64, 1), 256, 0, stream>>>(h2, idxT, w3b, b3, h3, N);
    // fc1: dense 128 -> 256, 2 column-blocks of 128. NSTEP=2.
    mfma_layer<128, 1, 128, 256, 64, 2, 2, false, 3>
        <<<dim3((N + 63) / 64, 2), 256, 0, stream>>>(h3, nullptr, f1b, fc1_b, h4, N);
    // fc2 + log_softmax
    fc2_kernel<<<(N + 31) / 32, 256, 0, stream>>>(h4, f2b, fc2_b, out, N);
}

// Round 10
// 276.022 us; speedup vs baseline: 1.5504x; 1.0047x over previous
//
#include <hip/hip_runtime.h>
#include <math.h>
#include <utility>

// N = 100000 nodes, SEQ = 16, layers: 3 ->16 ->32 ->64 ->128 ->256 ->12(log_softmax)
// bf16 MFMA, barrier-free K-loop, DEPTH-2 gather pipeline:
//   A (gathered): global_load_lds into per-wave TRIPLE-buffered LDS (DMA issued 2 steps
//     ahead). Chunk-XOR swizzle at the source address -> conflict-free ds_read_b128.
//   B: VGPR double-buffer from frag-major pre-swizzled weights (L2-resident).
//   Per-step issue order [B(s+1)] [DMA-A(s+2)] [idx(s+4)] so the compiler's automatic
//   B-register vmcnt wait does NOT force the in-flight A DMAs (they are younger).
//   Manual s_waitcnt vmcnt(N) (exact, per unrolled step) covers the LDS data dep.
//   sched_barrier(0xF) fences pin memory-op order but let ALU/MFMA cross.
//   NO __syncthreads in the K-loop. LDS reused for the coalesced C epilogue.
// R9 bug fixed here: loadB's step/ks term was missing the x8 elements-per-chunk
// factor (read wrong weights for every fragment except s=0,ks=0).

typedef __bf16 bf16x8 __attribute__((ext_vector_type(8)));
typedef float f32x16 __attribute__((ext_vector_type(16)));

template <int V> using ic = std::integral_constant<int, V>;

template <typename F, int... Is>
__device__ __forceinline__ void static_for_impl(F&& f, std::integer_sequence<int, Is...>) {
    (f(ic<Is>{}), ...);
}
template <int N_, typename F>
__device__ __forceinline__ void static_for(F&& f) {
    static_for_impl(static_cast<F&&>(f), std::make_integer_sequence<int, N_>{});
}

template <int N_>
__device__ __forceinline__ void wait_vmcnt() {
    static_assert(N_ <= 63, "vmcnt range");
    // gfx9 encoding: vmcnt[3:0] | expcnt<<4 | lgkmcnt<<8 | vmcnt[5:4]<<14 (exp/lgkm = no-wait)
    __builtin_amdgcn_s_waitcnt((N_ & 0xF) | (0x7 << 4) | (0xF << 8) | ((N_ >> 4) << 14));
}

// fence: pin VMEM/DS order, allow ALU/SALU/MFMA to cross
__device__ __forceinline__ void memfence_sched() { __builtin_amdgcn_sched_barrier(0x000F); }

__device__ __forceinline__ float elu_f(float v) { return v > 0.f ? v : expm1f(v); }

// ------------------------------------------------ weight prep: fp32 -> bf16, frag-major swizzle
// dst chunk ((k/64)*8 + (k%64)/8)*COUT + col, element k%8  <-  src[col*K + k]
template <int K, int C>
__device__ __forceinline__ void swz_one(const float* __restrict__ src, __bf16* __restrict__ dst, int j)
{
    int col = j / K;          // K is pow2
    int k = j & (K - 1);
    int chunk = ((k >> 6) * 8 + ((k & 63) >> 3)) * C + col;
    dst[chunk * 8 + (k & 7)] = (__bf16)src[j];
}

__global__ __launch_bounds__(256) void cvt_swz_kernel(const float* __restrict__ w1,
                                                      const float* __restrict__ w2,
                                                      const float* __restrict__ w3,
                                                      const float* __restrict__ f1,
                                                      const float* __restrict__ f2,
                                                      __bf16* __restrict__ d1,
                                                      __bf16* __restrict__ d2,
                                                      __bf16* __restrict__ d3,
                                                      __bf16* __restrict__ df1,
                                                      __bf16* __restrict__ df2)
{
    int i = blockIdx.x * 256 + threadIdx.x;
    if (i < 8192)        swz_one<256, 32>(w1, d1, i);
    else if (i < 40960)  swz_one<512, 64>(w2, d2, i - 8192);
    else if (i < 172032) swz_one<1024, 128>(w3, d3, i - 40960);
    else if (i < 204800) swz_one<128, 256>(f1, df1, i - 172032);
    else if (i < 207872) df2[i - 204800] = (__bf16)f2[i - 204800];   // fc2 stays row-major
}

// ------------------------------------------------ idx transpose: idxT[s*N + n] = idx[n*16 + s]
__global__ __launch_bounds__(256) void idxT_kernel(const int* __restrict__ idx,
                                                   int* __restrict__ idxT, int N)
{
    int i = blockIdx.x * 256 + threadIdx.x;
    if (i >= N * 16) return;
    int n = i >> 4, s = i & 15;
    idxT[s * N + n] = idx[i];
}

// ---------------------------------------------------------------- fc0: [N,3] -> [N,16] bf16
__global__ __launch_bounds__(256) void fc0_kernel(const float* __restrict__ x,
                                                  const float* __restrict__ w,
                                                  const float* __restrict__ b,
                                                  __bf16* __restrict__ h0, int N)
{
    int n = blockIdx.x * 256 + threadIdx.x;
    if (n >= N) return;
    float x0 = x[n * 3 + 0], x1 = x[n * 3 + 1], x2 = x[n * 3 + 2];
    __bf16 ob[16];
#pragma unroll
    for (int j = 0; j < 16; ++j)
        ob[j] = (__bf16)elu_f(w[j * 3 + 0] * x0 + w[j * 3 + 1] * x1 + w[j * 3 + 2] * x2 + b[j]);
    int4* dst = (int4*)&h0[(size_t)n * 16];
    dst[0] = *(int4*)&ob[0];
    dst[1] = *(int4*)&ob[8];
}

// ------------------------------------------- depth-2 pipelined MFMA gather-GEMM
template <int CIN, int S, int COUT_B, int COUT_TOT, int TILE_M, int RW, int CW,
          bool GATHER, int MINW, int NN>
__global__ __launch_bounds__(256, MINW) void mfma_layer(const __bf16* __restrict__ hin,
                                                        const int* __restrict__ idxT,
                                                        const __bf16* __restrict__ Wsw,
                                                        const float* __restrict__ bias,
                                                        __bf16* __restrict__ hout)
{
    constexpr int K = CIN * S;
    constexpr int NSTEP = K / 64;
    static_assert(K % 64 == 0, "K%64");
    constexpr int WM = TILE_M / RW;
    constexpr int WN = COUT_B / CW;
    constexpr int NT = WN / 32;
    constexpr int IPS = GATHER ? (64 / CIN) : 1;
    constexpr int D = WM / 8;              // DMA insts per step per wave (=4)
    constexpr int Bn = NT * 4;             // B vmem loads per step
    constexpr int I = GATHER ? D : 0;      // idx vmem loads per step
    constexpr int NBUFS = NSTEP < 3 ? NSTEP : 3;
    static_assert(RW * CW == 4, "4 waves");
    static_assert(WM == 32, "one 32-row subtile per wave");

    constexpr int AB = 4 * NBUFS * WM * 128;              // A staging bytes
    constexpr int CB = TILE_M * (COUT_B + 8) * 2;         // epilogue staging bytes
    constexpr int SH = AB > CB ? AB : CB;
    __shared__ __align__(16) char smem[SH];

    const int tid = threadIdx.x;
    const int lane = tid & 63;
    const int w = tid >> 6;
    const int wr = w / CW;
    const int wc = w % CW;
    const int ml = lane & 31;
    const int kh = lane >> 5;
    const int m0 = blockIdx.x * TILE_M;
    const int col0 = blockIdx.y * COUT_B;
    const int rbase = m0 + wr * WM;

    char* const Aw = smem + w * (NBUFS * WM * 128);   // this wave's A ring buffer

    // ---- per-lane DMA geometry (computed once)
    int ioff[GATHER ? D : 1];      // gather: j*NN + clamped row
    int koff[GATHER ? D : 1];      // gather: channel offset within node row
    int gmr[GATHER ? 1 : D];       // dense: clamped rows
    int coff[GATHER ? 1 : D];      // dense: chunk element offset
#pragma unroll
    for (int i = 0; i < D; ++i) {
        int r = i * 8 + (lane >> 3);
        int c = (lane & 7) ^ (r & 7);
        int gm = rbase + r; if (gm >= NN) gm = NN - 1;
        if constexpr (GATHER) {
            ioff[i] = ((c * 8) / CIN) * NN + gm;
            koff[i] = (c * 8) & (CIN - 1);
        } else {
            gmr[i] = gm;
            coff[i] = c * 8;
        }
    }

    bf16x8 bfr[2][NT][4];
    int myIdx[GATHER ? 3 : 1][GATHER ? D : 1];

    const __bf16* wlane = Wsw + ((size_t)(col0 + wc * WN + ml) + (size_t)kh * COUT_TOT) * 8;

    auto loadB = [&](auto sc) {
        constexpr int s = decltype(sc)::value;
        if constexpr (s < NSTEP) {
#pragma unroll
            for (int ni = 0; ni < NT; ++ni)
#pragma unroll
                for (int ks = 0; ks < 4; ++ks)
                    bfr[s & 1][ni][ks] = *(const bf16x8*)(wlane
                        + (size_t)(s * 8 + ks * 2) * COUT_TOT * 8 + ni * 32 * 8);
        }
    };
    auto loadIdxS = [&](auto sc) {
        constexpr int s = decltype(sc)::value;
        if constexpr (GATHER && s < NSTEP) {
#pragma unroll
            for (int i = 0; i < D; ++i)
                myIdx[s % 3][i] = idxT[(s * IPS) * NN + ioff[i]];
        }
    };
    auto issueDMA = [&](auto sc) {
        constexpr int s = decltype(sc)::value;
        if constexpr (s < NSTEP) {
            char* base = Aw + (s % NBUFS) * (WM * 128);
#pragma unroll
            for (int i = 0; i < D; ++i) {
                const __bf16* src;
                if constexpr (GATHER)
                    src = hin + (size_t)myIdx[s % 3][i] * CIN + koff[i];
                else
                    src = hin + (size_t)gmr[i] * K + s * 64 + coff[i];
                __builtin_amdgcn_global_load_lds(
                    (const __attribute__((address_space(1))) void*)src,
                    (__attribute__((address_space(3))) void*)(base + i * 1024),
                    16, 0, 0);
            }
        }
    };

    f32x16 acc[NT];
#pragma unroll
    for (int ni = 0; ni < NT; ++ni) { f32x16 z = {}; acc[ni] = z; }

    // ---- prologue (mirrors in-loop group order so vmcnt counts are exact)
    loadIdxS(ic<0>{});
    loadIdxS(ic<1>{});
    memfence_sched();
    issueDMA(ic<0>{});
    memfence_sched();
    loadIdxS(ic<2>{});
    memfence_sched();
    loadB(ic<0>{});
    memfence_sched();
    issueDMA(ic<1>{});
    memfence_sched();
    loadIdxS(ic<3>{});
    memfence_sched();

    // ---- K-loop: [B(s+1)] [DMA(s+2)] [idx(s+4)] | wait DMA(s) | ds_read + MFMA
    static_for<NSTEP>([&](auto sc) {
        constexpr int s = decltype(sc)::value;
        loadB(ic<s + 1>{});
        memfence_sched();
        issueDMA(ic<s + 2>{});
        memfence_sched();
        loadIdxS(ic<s + 4>{});
        memfence_sched();
        constexpr int NW = I * (s + 2 < NSTEP) + Bn + D * (s + 1 < NSTEP) + I * (s + 3 < NSTEP)
                         + Bn * (s + 1 < NSTEP) + D * (s + 2 < NSTEP) + I * (s + 4 < NSTEP);
        wait_vmcnt<NW>();                      // A(s) now resident in this wave's LDS buf
        memfence_sched();

        const char* base = Aw + (s % NBUFS) * (WM * 128);
        bf16x8 afr[4];
#pragma unroll
        for (int ks = 0; ks < 4; ++ks) {
            int cb = ks * 2 + kh;
            afr[ks] = *(const bf16x8*)(base + (ml * 8 + (cb ^ (ml & 7))) * 16);
        }
#pragma unroll
        for (int ks = 0; ks < 4; ++ks)
#pragma unroll
            for (int ni = 0; ni < NT; ++ni)
                acc[ni] = __builtin_amdgcn_mfma_f32_32x32x16_bf16(afr[ks], bfr[s & 1][ni][ks], acc[ni], 0, 0, 0);
    });

    // ---- epilogue: acc -> LDS (reuse A region) -> coalesced int4 stores
    __syncthreads();
    __bf16* Cs = (__bf16*)smem;
    constexpr int LDC = COUT_B + 8;
#pragma unroll
    for (int ni = 0; ni < NT; ++ni) {
        const int col = wc * WN + ni * 32 + ml;
        const float bv = bias[col0 + col];
#pragma unroll
        for (int r = 0; r < 16; ++r) {
            int row = wr * WM + ((r & 3) + 8 * (r >> 2) + 4 * kh);
            Cs[row * LDC + col] = (__bf16)elu_f(acc[ni][r] + bv);
        }
    }
    __syncthreads();
    constexpr int C8 = COUT_B / 8;
#pragma unroll
    for (int j2 = tid; j2 < TILE_M * C8; j2 += 256) {
        int row = j2 / C8, c8 = j2 % C8;
        int gm = m0 + row;
        if (gm < NN)
            *(int4*)&hout[(size_t)gm * COUT_TOT + col0 + c8 * 8] = *(int4*)&Cs[row * LDC + c8 * 8];
    }
}

// ---------------------------------------------------------------- fc2 + log_softmax: [N,256] bf16 -> [N,12] f32
__global__ __launch_bounds__(256) void fc2_kernel(const __bf16* __restrict__ h4,
                                                  const __bf16* __restrict__ Wb,  // [12,256] bf16
                                                  const float* __restrict__ bias,
                                                  float* __restrict__ out, int N)
{
    const int lane = threadIdx.x & 63;
    const int w = threadIdx.x >> 6;
    const int c = lane & 31;
    const int half = lane >> 5;

    bf16x8 wreg[12];
#pragma unroll
    for (int o = 0; o < 12; ++o)
        wreg[o] = *(const bf16x8*)&Wb[o * 256 + c * 8];

    const int base = blockIdx.x * 32 + w * 8;
#pragma unroll
    for (int p = 0; p < 4; ++p) {
        int n = base + p * 2 + half;
        bool valid = n < N;
        int nn = valid ? n : N - 1;
        bf16x8 h = *(const bf16x8*)&h4[(size_t)nn * 256 + c * 8];
        float hf[8];
#pragma unroll
        for (int j = 0; j < 8; ++j) hf[j] = (float)h[j];
        float pr[12];
#pragma unroll
        for (int o = 0; o < 12; ++o) {
            float s = 0.f;
#pragma unroll
            for (int j = 0; j < 8; ++j) s += hf[j] * (float)wreg[o][j];
            pr[o] = s;
        }
#pragma unroll
        for (int off = 16; off > 0; off >>= 1) {
#pragma unroll
            for (int o = 0; o < 12; ++o) pr[o] += __shfl_down(pr[o], off, 32);
        }
        if (c == 0 && valid) {
            float logits[12], mx = -1e30f;
#pragma unroll
            for (int o = 0; o < 12; ++o) {
                logits[o] = pr[o] + bias[o];
                mx = fmaxf(mx, logits[o]);
            }
            float s = 0.f;
#pragma unroll
            for (int o = 0; o < 12; ++o) s += expf(logits[o] - mx);
            float lse = mx + logf(s);
#pragma unroll
            for (int o = 0; o < 12; ++o) out[(size_t)n * 12 + o] = logits[o] - lse;
        }
    }
}

extern "C" void kernel_launch(void* const* d_in, const int* in_sizes, int n_in,
                              void* d_out, int out_size, void* d_ws, size_t ws_size,
                              hipStream_t stream)
{
    const int N = 100000;
    const float* x     = (const float*)d_in[0];
    const int*   idx   = (const int*)  d_in[1];
    const float* fc0_w = (const float*)d_in[2];
    const float* fc0_b = (const float*)d_in[3];
    const float* w1    = (const float*)d_in[4];
    const float* b1    = (const float*)d_in[5];
    const float* w2    = (const float*)d_in[6];
    const float* b2    = (const float*)d_in[7];
    const float* w3    = (const float*)d_in[8];
    const float* b3    = (const float*)d_in[9];
    const float* fc1_w = (const float*)d_in[10];
    const float* fc1_b = (const float*)d_in[11];
    const float* fc2_w = (const float*)d_in[12];
    const float* fc2_b = (const float*)d_in[13];
    float* out = (float*)d_out;

    // ---- workspace layout
    char* ws = (char*)d_ws;
    const int n_w1 = 32 * 256, n_w2 = 64 * 512, n_w3 = 128 * 1024, n_fc1 = 256 * 128, n_fc2 = 12 * 256;
    const int n_wb = n_w1 + n_w2 + n_w3 + n_fc1 + n_fc2;   // 207872
    __bf16* w1b = (__bf16*)ws;
    __bf16* w2b = w1b + n_w1;
    __bf16* w3b = w2b + n_w2;
    __bf16* f1b = w3b + n_w3;
    __bf16* f2b = f1b + n_fc1;
    size_t off = ((size_t)n_wb * 2 + 4095) & ~(size_t)4095;
    int* idxT = (int*)(ws + off);      off += (size_t)N * 16 * 4;
    __bf16* h0 = (__bf16*)(ws + off);  off += (size_t)N * 16 * 2;
    __bf16* h1 = (__bf16*)(ws + off);  off += (size_t)N * 32 * 2;
    __bf16* h2 = (__bf16*)(ws + off);  off += (size_t)N * 64 * 2;
    __bf16* h3 = (__bf16*)(ws + off);  off += (size_t)N * 128 * 2;
    __bf16* h4 = (__bf16*)(ws + off);  off += (size_t)N * 256 * 2;

    cvt_swz_kernel<<<(n_wb + 255) / 256, 256, 0, stream>>>(w1, w2, w3, fc1_w, fc2_w,
                                                           w1b, w2b, w3b, f1b, f2b);
    idxT_kernel<<<(N * 16 + 255) / 256, 256, 0, stream>>>(idx, idxT, N);
    fc0_kernel<<<(N + 255) / 256, 256, 0, stream>>>(x, fc0_w, fc0_b, h0, N);

    // spiral1: 16ch x16 -> 32. TILE 128 (RW=4, CW=1), NSTEP=4.
    mfma_layer<16, 16, 32, 32, 128, 4, 1, true, 3, 100000>
        <<<dim3((N + 127) / 128, 1), 256, 0, stream>>>(h0, idxT, w1b, b1, h1);
    // spiral2: 32ch x16 -> 64. TILE 64 (RW=2, CW=2), NSTEP=8.
    mfma_layer<32, 16, 64, 64, 64, 2, 2, true, 3, 100000>
        <<<dim3((N + 63) / 64, 1), 256, 0, stream>>>(h1, idxT, w2b, b2, h2);
    // spiral3: 64ch x16 -> 128. TILE 64 (RW=2, CW=2), NSTEP=16.
    mfma_layer<64, 16, 128, 128, 64, 2, 2, true, 3, 100000>
        <<<dim3((N + 63) / 64, 1), 256, 0, stream>>>(h2, idxT, w3b, b3, h3);
    // fc1: dense 128 -> 256, 2 column-blocks of 128. NSTEP=2 (all DMA in prologue).
    mfma_layer<128, 1, 128, 256, 64, 2, 2, false, 4, 100000>
        <<<dim3((N + 63) / 64, 2), 256, 0, stream>>>(h3, nullptr, f1b, fc1_b, h4);
    // fc2 + log_softmax
    fc2_kernel<<<(N + 31) / 32, 256, 0, stream>>>(h4, f2b, fc2_b, out, N);
}